// Round 5
// baseline (462.331 us; speedup 1.0000x reference)
//
#include <hip/hip_runtime.h>
#include <math.h>

#define L_SEQ 2048
#define DMOD  1024
#define DIN   2048
#define NBATCH 2
#define NTOK  (NBATCH * L_SEQ)   // 4096 tokens
#define NST   16
#define RRANK 64
#define LOG2E 1.44269504088896f

#define GCHUNK 64                 // chunks along L
#define CLEN   (L_SEQ / GCHUNK)   // 32 steps per chunk
#define SCHUNK 8                  // LDS staging depth

typedef __attribute__((ext_vector_type(8))) short  short8;   // 8 bf16
typedef __attribute__((ext_vector_type(4))) float  f32x4;

// round-to-nearest-even fp32 -> bf16
__device__ __forceinline__ ushort f2bf(float f) {
    unsigned u = __float_as_uint(f);
    u += 0x7fffu + ((u >> 16) & 1u);
    return (ushort)(u >> 16);
}

// async global->LDS DMA, 16 B per lane; lds dest = wave-uniform base + lane*16
__device__ __forceinline__ void gload16(const ushort* g, ushort* l) {
    __builtin_amdgcn_global_load_lds(
        (const __attribute__((address_space(1))) unsigned int*)g,
        (__attribute__((address_space(3))) unsigned int*)l,
        16, 0, 0);
}

// ---------------------------------------------------------------------------
// Flat cast fp32 -> bf16, 8 elements/thread.
// ---------------------------------------------------------------------------
__global__ __launch_bounds__(256) void cast_bf16_k(
    const float* __restrict__ src, ushort* __restrict__ dst)
{
    int i = (blockIdx.x * 256 + threadIdx.x) * 8;
    float4 a = *(const float4*)(src + i);
    float4 b = *(const float4*)(src + i + 4);
    ushort4 o0 = make_ushort4(f2bf(a.x), f2bf(a.y), f2bf(a.z), f2bf(a.w));
    ushort4 o1 = make_ushort4(f2bf(b.x), f2bf(b.y), f2bf(b.z), f2bf(b.w));
    *(ushort4*)(dst + i)     = o0;
    *(ushort4*)(dst + i + 4) = o1;
}

// ---------------------------------------------------------------------------
// Strided cast: dtb[4096][64] bf16 <- dbc[4096][96] cols 0:64.
// ---------------------------------------------------------------------------
__global__ __launch_bounds__(256) void cast_dt_k(
    const float* __restrict__ dbc, ushort* __restrict__ dtb)
{
    int gid = blockIdx.x * 256 + threadIdx.x;   // 0..32767
    int i   = gid * 8;
    int row = i >> 6, col = i & 63;
    const float* p = dbc + (size_t)row * 96 + col;
    float4 a = *(const float4*)p;
    float4 b = *(const float4*)(p + 4);
    ushort* q = dtb + (size_t)row * 64 + col;
    q[0] = f2bf(a.x); q[1] = f2bf(a.y); q[2] = f2bf(a.z); q[3] = f2bf(a.w);
    q[4] = f2bf(b.x); q[5] = f2bf(b.y); q[6] = f2bf(b.z); q[7] = f2bf(b.w);
}

// ---------------------------------------------------------------------------
// Transpose + cast: src fp32 [R][C] -> dst bf16 [C][R]. 32x32 LDS tile.
// ---------------------------------------------------------------------------
__global__ __launch_bounds__(256) void tcast_k(
    const float* __restrict__ src, ushort* __restrict__ dst, int R, int C)
{
    __shared__ float t[32][33];
    int tx  = threadIdx.x & 31;
    int ty  = threadIdx.x >> 5;        // 0..7
    int c0  = blockIdx.x * 32;
    int r0  = blockIdx.y * 32;
    #pragma unroll
    for (int i = 0; i < 4; ++i)
        t[ty + i * 8][tx] = src[(size_t)(r0 + ty + i * 8) * C + c0 + tx];
    __syncthreads();
    #pragma unroll
    for (int i = 0; i < 4; ++i)
        dst[(size_t)(c0 + ty + i * 8) * R + r0 + tx] = f2bf(t[tx][ty + i * 8]);
}

// ---------------------------------------------------------------------------
// bf16 MFMA GEMM (m97-style): C(M,N) fp32 = A(M,K) @ Bt(N,K)^T.
// 128x128 tile, BK=32, 256 thr = 4 waves, global_load_lds 16B staging into
// unpadded [row][32] LDS tiles. EPI=1: softplus(acc + bias[col]).
// Requires M%128==0, N%128==0, K%32==0.
// ---------------------------------------------------------------------------
template<int EPI>
__global__ __launch_bounds__(256) void gemm_mfma(
    const ushort* __restrict__ A,   // [M][K] bf16
    const ushort* __restrict__ Bt,  // [N][K] bf16
    float* __restrict__ C,          // fp32, leading dim ldc
    int M, int N, int K, int ldc, const float* __restrict__ bias)
{
    __shared__ ushort As[128 * 32];
    __shared__ ushort Bs[128 * 32];

    const int tid  = threadIdx.x;
    const int wave = tid >> 6;
    const int lane = tid & 63;
    const int wm   = (wave & 1) * 64;
    const int wn   = (wave >> 1) * 64;
    const int m0   = blockIdx.y * 128;
    const int n0   = blockIdx.x * 128;

    const int rsub = lane >> 2;         // 0..15 : row within 16-row group
    const int ksub = (lane & 3) * 8;    // 0,8,16,24 halfs
    const int lrow = lane & 15;
    const int kq   = (lane >> 4) * 8;

    // hoisted staging pointers (per-lane global, wave-uniform LDS)
    const ushort* gA0 = A  + (size_t)(m0 + wave * 32 + rsub)      * K + ksub;
    const ushort* gA1 = A  + (size_t)(m0 + wave * 32 + 16 + rsub) * K + ksub;
    const ushort* gB0 = Bt + (size_t)(n0 + wave * 32 + rsub)      * K + ksub;
    const ushort* gB1 = Bt + (size_t)(n0 + wave * 32 + 16 + rsub) * K + ksub;
    ushort* lA0 = As + (wave * 32)      * 32;
    ushort* lA1 = As + (wave * 32 + 16) * 32;
    ushort* lB0 = Bs + (wave * 32)      * 32;
    ushort* lB1 = Bs + (wave * 32 + 16) * 32;

    f32x4 acc[4][4];
    #pragma unroll
    for (int i = 0; i < 4; ++i)
        #pragma unroll
        for (int j = 0; j < 4; ++j)
            acc[i][j] = (f32x4){0.f, 0.f, 0.f, 0.f};

    for (int k0 = 0; k0 < K; k0 += 32) {
        __syncthreads();   // prior iteration's ds_reads done
        gload16(gA0 + k0, lA0);
        gload16(gA1 + k0, lA1);
        gload16(gB0 + k0, lB0);
        gload16(gB1 + k0, lB1);
        __syncthreads();   // compiler drains vmcnt before barrier

        short8 af[4], bfr[4];
        #pragma unroll
        for (int i = 0; i < 4; ++i) {
            af[i]  = *(const short8*)&As[(wm + i * 16 + lrow) * 32 + kq];
            bfr[i] = *(const short8*)&Bs[(wn + i * 16 + lrow) * 32 + kq];
        }
        #pragma unroll
        for (int i = 0; i < 4; ++i)
            #pragma unroll
            for (int j = 0; j < 4; ++j)
                acc[i][j] = __builtin_amdgcn_mfma_f32_16x16x32_bf16(
                    af[i], bfr[j], acc[i][j], 0, 0, 0);
    }

    // C/D layout: col = lane&15, row = (lane>>4)*4 + reg
    const int rb = m0 + wm + ((lane >> 4) << 2);
    const int cb = n0 + wn + lrow;
    #pragma unroll
    for (int i = 0; i < 4; ++i)
        #pragma unroll
        for (int j = 0; j < 4; ++j)
            #pragma unroll
            for (int r = 0; r < 4; ++r) {
                float v = acc[i][j][r];
                int col = cb + j * 16;
                if (EPI == 1) {
                    v += bias[col];
                    v = (v > 20.f) ? v : log1pf(__expf(v));  // softplus
                }
                C[(size_t)(rb + i * 16 + r) * ldc + col] = v;
            }
}

// ---------------------------------------------------------------------------
// GEMM2 split-K: part[ks] = uconv[:, ks*256:(ks+1)*256] @ W_x[slice].
// ---------------------------------------------------------------------------
#define G2_KSPLIT 8
#define G2_KC     256
#define G2_STAGE  64
__global__ __launch_bounds__(256) void gemm2_splitk(
    const float* __restrict__ A,    // [4096][2048] = uconv
    const float* __restrict__ B,    // [2048][96]   = W_x
    float* __restrict__ part)       // [8][4096][96]
{
    __shared__ float AsT[G2_STAGE][65];
    __shared__ float Bs[G2_STAGE][96];

    const int tid = threadIdx.x;
    const int ks  = blockIdx.x;
    const int m0  = blockIdx.y * 64;
    const int tx  = tid & 15;       // 6 cols each
    const int ty  = tid >> 4;       // 4 rows each

    float acc[4][6] = {};

    for (int st = 0; st < G2_KC / G2_STAGE; ++st) {
        const int k0 = ks * G2_KC + st * G2_STAGE;
        float4 av[4];
        #pragma unroll
        for (int i = 0; i < 4; ++i) {
            int idx = tid + 256 * i;
            int row = idx >> 4, c4 = idx & 15;
            av[i] = *(const float4*)(A + (size_t)(m0 + row) * 2048 + k0 + c4 * 4);
        }
        float4 bv[6];
        #pragma unroll
        for (int i = 0; i < 6; ++i) {
            int idx = tid + 256 * i;
            int row = idx / 24, c4 = idx % 24;
            bv[i] = *(const float4*)(B + (size_t)(k0 + row) * 96 + c4 * 4);
        }
        __syncthreads();
        #pragma unroll
        for (int i = 0; i < 4; ++i) {
            int idx = tid + 256 * i;
            int row = idx >> 4, c4 = idx & 15;
            AsT[c4 * 4 + 0][row] = av[i].x;
            AsT[c4 * 4 + 1][row] = av[i].y;
            AsT[c4 * 4 + 2][row] = av[i].z;
            AsT[c4 * 4 + 3][row] = av[i].w;
        }
        #pragma unroll
        for (int i = 0; i < 6; ++i) {
            int idx = tid + 256 * i;
            int row = idx / 24, c4 = idx % 24;
            *(float4*)&Bs[row][c4 * 4] = bv[i];
        }
        __syncthreads();

        #pragma unroll 8
        for (int kk = 0; kk < G2_STAGE; ++kk) {
            float a[4], b[6];
            #pragma unroll
            for (int r = 0; r < 4; ++r) a[r] = AsT[kk][ty * 4 + r];
            #pragma unroll
            for (int c = 0; c < 6; ++c) b[c] = Bs[kk][tx * 6 + c];
            #pragma unroll
            for (int r = 0; r < 4; ++r)
                #pragma unroll
                for (int c = 0; c < 6; ++c)
                    acc[r][c] += a[r] * b[c];
        }
    }

    float* po = part + (size_t)ks * NTOK * 96;
    #pragma unroll
    for (int r = 0; r < 4; ++r)
        #pragma unroll
        for (int c = 0; c < 6; ++c)
            po[(size_t)(m0 + ty * 4 + r) * 96 + tx * 6 + c] = acc[r][c];
}

__global__ __launch_bounds__(256) void gemm2_reduce(
    const float* __restrict__ part, float* __restrict__ dbc)
{
    int i = (blockIdx.x * 256 + threadIdx.x) * 4;
    float4 s = *(const float4*)(part + i);
    #pragma unroll
    for (int ks = 1; ks < G2_KSPLIT; ++ks) {
        float4 v = *(const float4*)(part + (size_t)ks * NTOK * 96 + i);
        s.x += v.x; s.y += v.y; s.z += v.z; s.w += v.w;
    }
    *(float4*)(dbc + i) = s;
}

// ---------------------------------------------------------------------------
// Causal depthwise conv (K=4) + SiLU.
// ---------------------------------------------------------------------------
__global__ __launch_bounds__(256) void conv_silu_k(
    const float* __restrict__ xz, const float* __restrict__ w_conv,
    const float* __restrict__ b_conv, float* __restrict__ uconv)
{
    int idx   = blockIdx.x * 256 + threadIdx.x;
    int d     = idx & (DIN - 1);
    int token = idx >> 11;
    int t     = token & (L_SEQ - 1);

    float acc = b_conv[d];
    #pragma unroll
    for (int k = 0; k < 4; ++k) {
        int tt = t - 3 + k;
        if (tt >= 0)
            acc += xz[(size_t)(token - 3 + k) * 4096 + d] * w_conv[d * 4 + k];
    }
    float s = acc / (1.f + expf(-acc));
    uconv[(size_t)token * DIN + d] = s;
}

// ---------------------------------------------------------------------------
// Chunked selective scan, pass 1: 2*32*64 = 4096 blocks x 64 thr.
// ---------------------------------------------------------------------------
__global__ __launch_bounds__(64) void scan_part1(
    const float* __restrict__ xz,      // delta in cols 0:2048
    const float* __restrict__ uconv,
    const float* __restrict__ dbc,
    const float* __restrict__ A_log,
    float* __restrict__ c_out,         // [2][2048][64][16]
    float* __restrict__ dsum_out)      // [2][2048][64]
{
    int chunk = blockIdx.x & 63;
    int dg    = (blockIdx.x >> 6) & 31;
    int b     = blockIdx.x >> 11;
    int tid   = threadIdx.x;
    int d     = dg * 64 + tid;

    __shared__ float sDelta[SCHUNK][64];
    __shared__ float sU[SCHUNK][64];
    __shared__ float sB[SCHUNK][16];

    float Al[NST];
    #pragma unroll
    for (int n = 0; n < NST; ++n)
        Al[n] = -expf(A_log[(size_t)d * NST + n]) * LOG2E;

    float h[NST];
    #pragma unroll
    for (int n = 0; n < NST; ++n) h[n] = 0.f;
    float dsum = 0.f;

    const size_t tokbase = (size_t)b * L_SEQ + (size_t)chunk * CLEN;

    for (int t0 = 0; t0 < CLEN; t0 += SCHUNK) {
        const size_t tk0 = tokbase + t0;
        __syncthreads();
        #pragma unroll
        for (int i = 0; i < SCHUNK; ++i) {
            sDelta[i][tid] = xz[(tk0 + i) * 4096 + dg * 64 + tid];
            sU[i][tid]     = uconv[(tk0 + i) * 2048 + dg * 64 + tid];
        }
        #pragma unroll
        for (int i = 0; i < SCHUNK * 16 / 64; ++i) {
            int e = i * 64 + tid;
            int s = e >> 4, n = e & 15;
            sB[s][n] = dbc[(tk0 + s) * 96 + RRANK + n];
        }
        __syncthreads();

        #pragma unroll 4
        for (int s = 0; s < SCHUNK; ++s) {
            float delta = sDelta[s][tid];
            float u     = sU[s][tid];
            float du    = delta * u;
            dsum += delta;
            #pragma unroll
            for (int q = 0; q < 4; ++q) {
                float4 bq = *(const float4*)&sB[s][q * 4];
                h[q*4+0] = h[q*4+0] * exp2f(delta * Al[q*4+0]) + du * bq.x;
                h[q*4+1] = h[q*4+1] * exp2f(delta * Al[q*4+1]) + du * bq.y;
                h[q*4+2] = h[q*4+2] * exp2f(delta * Al[q*4+2]) + du * bq.z;
                h[q*4+3] = h[q*4+3] * exp2f(delta * Al[q*4+3]) + du * bq.w;
            }
        }
    }

    size_t base = (((size_t)b * DIN + d) * GCHUNK + chunk) * NST;
    #pragma unroll
    for (int q = 0; q < 4; ++q)
        *(float4*)&c_out[base + q * 4] = make_float4(h[q*4], h[q*4+1], h[q*4+2], h[q*4+3]);
    dsum_out[((size_t)b * DIN + d) * GCHUNK + chunk] = dsum;
}

// ---------------------------------------------------------------------------
// Pass 2: per (b,d,n) scan the 64 chunk summaries, IN PLACE over c_buf:
// c_buf[ch] becomes h_start[ch].
// ---------------------------------------------------------------------------
__global__ __launch_bounds__(256) void scan_part2(
    float* __restrict__ cbuf,           // [2][2048][64][16] in: c, out: h_start
    const float* __restrict__ dsum_in,  // [2][2048][64]
    const float* __restrict__ A_log)
{
    int idx = blockIdx.x * 256 + threadIdx.x;
    int n   = idx & 15;
    int d   = (idx >> 4) & (DIN - 1);
    int b   = idx >> 15;

    float Al = -expf(A_log[(size_t)d * NST + n]) * LOG2E;
    size_t cb = ((size_t)b * DIN + d) * GCHUNK;

    float h = 0.f;
    for (int ch = 0; ch < GCHUNK; ++ch) {
        size_t o = (cb + ch) * NST + n;
        float c  = cbuf[o];
        float dA = exp2f(Al * dsum_in[cb + ch]);
        cbuf[o]  = h;
        h = h * dA + c;
    }
}

// ---------------------------------------------------------------------------
// Pass 3: re-run chunks from h_start (= cbuf), y + gating epilogue.
// ---------------------------------------------------------------------------
__global__ __launch_bounds__(64) void scan_part3(
    const float* __restrict__ xz,       // delta cols 0:2048, z cols 2048:4096
    float* __restrict__ uconv,          // in: u, out: y
    const float* __restrict__ dbc,
    const float* __restrict__ A_log,
    const float* __restrict__ Dp,
    const float* __restrict__ h_start)
{
    int chunk = blockIdx.x & 63;
    int dg    = (blockIdx.x >> 6) & 31;
    int b     = blockIdx.x >> 11;
    int tid   = threadIdx.x;
    int d     = dg * 64 + tid;

    __shared__ float sDelta[SCHUNK][64];
    __shared__ float sU[SCHUNK][64];
    __shared__ float sZ[SCHUNK][64];
    __shared__ float sBC[SCHUNK][32];   // [s][0:16]=B, [s][16:32]=C

    float Al[NST];
    #pragma unroll
    for (int n = 0; n < NST; ++n)
        Al[n] = -expf(A_log[(size_t)d * NST + n]) * LOG2E;
    float Dd = Dp[d];

    float h[NST];
    size_t hb = (((size_t)b * DIN + d) * GCHUNK + chunk) * NST;
    #pragma unroll
    for (int q = 0; q < 4; ++q) {
        float4 v = *(const float4*)&h_start[hb + q * 4];
        h[q*4] = v.x; h[q*4+1] = v.y; h[q*4+2] = v.z; h[q*4+3] = v.w;
    }

    const size_t tokbase = (size_t)b * L_SEQ + (size_t)chunk * CLEN;

    for (int t0 = 0; t0 < CLEN; t0 += SCHUNK) {
        const size_t tk0 = tokbase + t0;
        __syncthreads();
        #pragma unroll
        for (int i = 0; i < SCHUNK; ++i) {
            sDelta[i][tid] = xz[(tk0 + i) * 4096 + dg * 64 + tid];
            sU[i][tid]     = uconv[(tk0 + i) * 2048 + dg * 64 + tid];
            sZ[i][tid]     = xz[(tk0 + i) * 4096 + 2048 + dg * 64 + tid];
        }
        #pragma unroll
        for (int i = 0; i < SCHUNK * 32 / 64; ++i) {
            int e = i * 64 + tid;
            int s = e >> 5, cc = e & 31;
            sBC[s][cc] = dbc[(tk0 + s) * 96 + RRANK + cc];
        }
        __syncthreads();

        for (int s = 0; s < SCHUNK; ++s) {
            float delta = sDelta[s][tid];
            float u     = sU[s][tid];
            float du    = delta * u;
            float y = 0.f;
            #pragma unroll
            for (int q = 0; q < 4; ++q) {
                float4 bq = *(const float4*)&sBC[s][q * 4];
                float4 cq = *(const float4*)&sBC[s][16 + q * 4];
                h[q*4+0] = h[q*4+0] * exp2f(delta * Al[q*4+0]) + du * bq.x; y += h[q*4+0] * cq.x;
                h[q*4+1] = h[q*4+1] * exp2f(delta * Al[q*4+1]) + du * bq.y; y += h[q*4+1] * cq.y;
                h[q*4+2] = h[q*4+2] * exp2f(delta * Al[q*4+2]) + du * bq.z; y += h[q*4+2] * cq.z;
                h[q*4+3] = h[q*4+3] * exp2f(delta * Al[q*4+3]) + du * bq.w; y += h[q*4+3] * cq.w;
            }
            float z  = sZ[s][tid];
            float sz = z / (1.f + __expf(-z));
            uconv[(tk0 + s) * 2048 + d] = (y + u * Dd) * sz;
        }
    }
}

// ---------------------------------------------------------------------------
// LayerNorm over DM + residual.
// ---------------------------------------------------------------------------
__global__ __launch_bounds__(256) void ln_k(
    const float* __restrict__ outpre, const float* __restrict__ x,
    const float* __restrict__ gamma, const float* __restrict__ beta,
    float* __restrict__ out)
{
    int row = blockIdx.x;
    int tid = threadIdx.x;
    const float* rp = outpre + (size_t)row * DMOD;
    float4 v = ((const float4*)rp)[tid];

    float s  = v.x + v.y + v.z + v.w;
    float s2 = v.x * v.x + v.y * v.y + v.z * v.z + v.w * v.w;
    #pragma unroll
    for (int off = 32; off > 0; off >>= 1) {
        s  += __shfl_down(s, off);
        s2 += __shfl_down(s2, off);
    }
    __shared__ float ws[4], ws2[4];
    int wave = tid >> 6, lane = tid & 63;
    if (lane == 0) { ws[wave] = s; ws2[wave] = s2; }
    __syncthreads();
    if (tid == 0) {
        float ts = 0.f, ts2 = 0.f;
        #pragma unroll
        for (int w = 0; w < 4; ++w) { ts += ws[w]; ts2 += ws2[w]; }
        ws[0] = ts; ws2[0] = ts2;
    }
    __syncthreads();
    float mu  = ws[0] * (1.f / DMOD);
    float var = ws2[0] * (1.f / DMOD) - mu * mu;
    float rs  = rsqrtf(var + 1e-5f);

    float4 g  = ((const float4*)gamma)[tid];
    float4 be = ((const float4*)beta)[tid];
    float4 xr = ((const float4*)(x + (size_t)row * DMOD))[tid];
    float4 o;
    o.x = (v.x - mu) * rs * g.x + be.x + xr.x;
    o.y = (v.y - mu) * rs * g.y + be.y + xr.y;
    o.z = (v.z - mu) * rs * g.z + be.z + xr.z;
    o.w = (v.w - mu) * rs * g.w + be.w + xr.w;
    ((float4*)(out + (size_t)row * DMOD))[tid] = o;
}

// ---------------------------------------------------------------------------
extern "C" void kernel_launch(void* const* d_in, const int* in_sizes, int n_in,
                              void* d_out, int out_size, void* d_ws, size_t ws_size,
                              hipStream_t stream)
{
    const float* x      = (const float*)d_in[0];
    const float* W_in   = (const float*)d_in[1];
    const float* w_conv = (const float*)d_in[2];
    const float* b_conv = (const float*)d_in[3];
    const float* W_x    = (const float*)d_in[4];
    const float* W_dt   = (const float*)d_in[5];
    const float* b_dt   = (const float*)d_in[6];
    const float* A_log  = (const float*)d_in[7];
    const float* Dp     = (const float*)d_in[8];
    const float* W_out  = (const float*)d_in[9];
    const float* gamma  = (const float*)d_in[10];
    const float* beta   = (const float*)d_in[11];
    float* out = (float*)d_out;

    char* ws = (char*)d_ws;
    const size_t MB = 1024 * 1024;
    float* xz     = (float*)(ws);                            // [4096][4096] (64 MB)
    float* uconv  = (float*)(ws + 64 * MB);                  // [4096][2048] (32 MB)
    float* dbc    = (float*)(ws + 96 * MB);                  // [4096][96]   (1.5 MB)
    float* dsum   = (float*)(ws + 96 * MB + 1536 * 1024);    // [2][2048][64] (1 MB) 96+1.5..98.5
    float* c_buf  = (float*)(ws + 98 * MB + 512 * 1024);     // [2][2048][64][16] (16 MB) 98.5-114.5
    // pre-GEMM1 (dead after gemm_mfma #1):
    ushort* xb    = (ushort*)(ws + 98 * MB + 512 * 1024);    // [4096][1024] bf16 (8 MB)
    ushort* Wib   = (ushort*)(ws + 106 * MB + 512 * 1024);   // [4096][1024] bf16 (8 MB)
    // GEMM2 phase (dead after reduce):
    float* g2part = (float*)(ws + 98 * MB + 512 * 1024);     // [8][4096][96] (12.6 MB)
    // GEMM3 phase (dead after gemm_mfma #3; before scan writes c_buf):
    ushort* dtb   = (ushort*)(ws + 98 * MB + 512 * 1024);    // [4096][64] bf16 (0.5 MB)
    ushort* Wdtb  = (ushort*)(ws + 99 * MB + 512 * 1024);    // [2048][64] bf16 (0.25 MB)
    // post-scan phase (xz dead after scan_part3):
    ushort* yb    = (ushort*)(ws);                           // [4096][2048] bf16 (16 MB)
    ushort* Wob   = (ushort*)(ws + 16 * MB);                 // [1024][2048] bf16 (4 MB)
    float* outpre = (float*)(ws + 32 * MB);                  // [4096][1024] (16 MB)

    dim3 blk(256);

    // 0a. x -> bf16
    cast_bf16_k<<<dim3(NTOK * DMOD / 2048), blk, 0, stream>>>(x, xb);
    // 0b. W_in (1024 x 4096) -> W_in^T bf16 (4096 x 1024)
    tcast_k<<<dim3(4096 / 32, 1024 / 32), blk, 0, stream>>>(W_in, Wib, 1024, 4096);
    // 1. xz = x @ W_in   (MFMA bf16, global_load_lds)
    gemm_mfma<0><<<dim3(4096 / 128, 4096 / 128), blk, 0, stream>>>(
        xb, Wib, xz, 4096, 4096, 1024, 4096, nullptr);
    // 2. u = silu(causal_conv(u)) -> uconv
    conv_silu_k<<<dim3(NTOK * DIN / 256), blk, 0, stream>>>(xz, w_conv, b_conv, uconv);
    // 3. dbc = u @ W_x  (fp32 split-K + reduce)
    gemm2_splitk<<<dim3(G2_KSPLIT, 64), blk, 0, stream>>>(uconv, W_x, g2part);
    gemm2_reduce<<<dim3(NTOK * 96 / 4 / 256), blk, 0, stream>>>(g2part, dbc);
    // 4. delta = softplus(dt @ W_dt + b_dt) -> u-half of xz  (MFMA bf16)
    cast_dt_k<<<dim3(NTOK * 64 / 8 / 256), blk, 0, stream>>>(dbc, dtb);
    tcast_k<<<dim3(2048 / 32, 64 / 32), blk, 0, stream>>>(W_dt, Wdtb, 64, 2048);
    gemm_mfma<1><<<dim3(2048 / 128, 4096 / 128), blk, 0, stream>>>(
        dtb, Wdtb, xz, 4096, 2048, 64, 4096, b_dt);
    // 5. chunked selective scan -> y overwrites uconv
    scan_part1<<<dim3(NBATCH * 32 * GCHUNK), dim3(64), 0, stream>>>(
        xz, uconv, dbc, A_log, c_buf, dsum);
    scan_part2<<<dim3(NBATCH * DIN * NST / 256), blk, 0, stream>>>(
        c_buf, dsum, A_log);
    scan_part3<<<dim3(NBATCH * 32 * GCHUNK), dim3(64), 0, stream>>>(
        xz, uconv, dbc, A_log, Dp, c_buf);
    // 6a. y -> bf16 (xz region is dead now)
    cast_bf16_k<<<dim3(NTOK * DIN / 2048), blk, 0, stream>>>(uconv, yb);
    // 6b. W_out (2048 x 1024) -> W_out^T bf16 (1024 x 2048)
    tcast_k<<<dim3(1024 / 32, 2048 / 32), blk, 0, stream>>>(W_out, Wob, 2048, 1024);
    // 6c. out_pre = y @ W_out  (MFMA bf16)
    gemm_mfma<0><<<dim3(1024 / 128, 4096 / 128), blk, 0, stream>>>(
        yb, Wob, outpre, 4096, 1024, 2048, 1024, nullptr);
    // 7. LayerNorm + residual
    ln_k<<<dim3(NTOK), blk, 0, stream>>>(outpre, x, gamma, beta, out);
}

// Round 6
// 424.293 us; speedup vs baseline: 1.0897x; 1.0897x over previous
//
#include <hip/hip_runtime.h>
#include <math.h>

#define L_SEQ 2048
#define DMOD  1024
#define DIN   2048
#define NBATCH 2
#define NTOK  (NBATCH * L_SEQ)   // 4096 tokens
#define NST   16
#define RRANK 64
#define LOG2E 1.44269504088896f

#define GCHUNK 64                 // chunks along L
#define CLEN   (L_SEQ / GCHUNK)   // 32 steps per chunk
#define SCHUNK 8                  // software-pipeline stage depth
#define NSTAGE (CLEN / SCHUNK)    // 4 stages per chunk

typedef __attribute__((ext_vector_type(8))) short  short8;   // 8 bf16
typedef __attribute__((ext_vector_type(4))) float  f32x4;

// round-to-nearest-even fp32 -> bf16
__device__ __forceinline__ ushort f2bf(float f) {
    unsigned u = __float_as_uint(f);
    u += 0x7fffu + ((u >> 16) & 1u);
    return (ushort)(u >> 16);
}

__device__ __forceinline__ float fexp2(float x) {
    return __builtin_amdgcn_exp2f(x);   // raw v_exp_f32
}

// async global->LDS DMA, 16 B per lane; lds dest = wave-uniform base + lane*16
__device__ __forceinline__ void gload16(const ushort* g, ushort* l) {
    __builtin_amdgcn_global_load_lds(
        (const __attribute__((address_space(1))) unsigned int*)g,
        (__attribute__((address_space(3))) unsigned int*)l,
        16, 0, 0);
}

// ---------------------------------------------------------------------------
// Flat cast fp32 -> bf16, 8 elements/thread.
// ---------------------------------------------------------------------------
__global__ __launch_bounds__(256) void cast_bf16_k(
    const float* __restrict__ src, ushort* __restrict__ dst)
{
    int i = (blockIdx.x * 256 + threadIdx.x) * 8;
    float4 a = *(const float4*)(src + i);
    float4 b = *(const float4*)(src + i + 4);
    ushort4 o0 = make_ushort4(f2bf(a.x), f2bf(a.y), f2bf(a.z), f2bf(a.w));
    ushort4 o1 = make_ushort4(f2bf(b.x), f2bf(b.y), f2bf(b.z), f2bf(b.w));
    *(ushort4*)(dst + i)     = o0;
    *(ushort4*)(dst + i + 4) = o1;
}

// ---------------------------------------------------------------------------
// Strided cast: dtb[4096][64] bf16 <- dbc[4096][96] cols 0:64.
// ---------------------------------------------------------------------------
__global__ __launch_bounds__(256) void cast_dt_k(
    const float* __restrict__ dbc, ushort* __restrict__ dtb)
{
    int gid = blockIdx.x * 256 + threadIdx.x;   // 0..32767
    int i   = gid * 8;
    int row = i >> 6, col = i & 63;
    const float* p = dbc + (size_t)row * 96 + col;
    float4 a = *(const float4*)p;
    float4 b = *(const float4*)(p + 4);
    ushort* q = dtb + (size_t)row * 64 + col;
    q[0] = f2bf(a.x); q[1] = f2bf(a.y); q[2] = f2bf(a.z); q[3] = f2bf(a.w);
    q[4] = f2bf(b.x); q[5] = f2bf(b.y); q[6] = f2bf(b.z); q[7] = f2bf(b.w);
}

// ---------------------------------------------------------------------------
// Transpose + cast: src fp32 [R][C] -> dst bf16 [C][R]. 32x32 LDS tile.
// ---------------------------------------------------------------------------
__global__ __launch_bounds__(256) void tcast_k(
    const float* __restrict__ src, ushort* __restrict__ dst, int R, int C)
{
    __shared__ float t[32][33];
    int tx  = threadIdx.x & 31;
    int ty  = threadIdx.x >> 5;        // 0..7
    int c0  = blockIdx.x * 32;
    int r0  = blockIdx.y * 32;
    #pragma unroll
    for (int i = 0; i < 4; ++i)
        t[ty + i * 8][tx] = src[(size_t)(r0 + ty + i * 8) * C + c0 + tx];
    __syncthreads();
    #pragma unroll
    for (int i = 0; i < 4; ++i)
        dst[(size_t)(c0 + ty + i * 8) * R + r0 + tx] = f2bf(t[tx][ty + i * 8]);
}

// ---------------------------------------------------------------------------
// bf16 MFMA GEMM (m97-style): C(M,N) fp32 = A(M,K) @ Bt(N,K)^T.
// 128x128 tile, BK=32, 256 thr = 4 waves, global_load_lds 16B staging.
// EPI=1: softplus(acc + bias[col]).
// ---------------------------------------------------------------------------
template<int EPI>
__global__ __launch_bounds__(256) void gemm_mfma(
    const ushort* __restrict__ A,   // [M][K] bf16
    const ushort* __restrict__ Bt,  // [N][K] bf16
    float* __restrict__ C,          // fp32, leading dim ldc
    int M, int N, int K, int ldc, const float* __restrict__ bias)
{
    __shared__ ushort As[128 * 32];
    __shared__ ushort Bs[128 * 32];

    const int tid  = threadIdx.x;
    const int wave = tid >> 6;
    const int lane = tid & 63;
    const int wm   = (wave & 1) * 64;
    const int wn   = (wave >> 1) * 64;
    const int m0   = blockIdx.y * 128;
    const int n0   = blockIdx.x * 128;

    const int rsub = lane >> 2;         // 0..15
    const int ksub = (lane & 3) * 8;    // 0,8,16,24 halfs
    const int lrow = lane & 15;
    const int kq   = (lane >> 4) * 8;

    const ushort* gA0 = A  + (size_t)(m0 + wave * 32 + rsub)      * K + ksub;
    const ushort* gA1 = A  + (size_t)(m0 + wave * 32 + 16 + rsub) * K + ksub;
    const ushort* gB0 = Bt + (size_t)(n0 + wave * 32 + rsub)      * K + ksub;
    const ushort* gB1 = Bt + (size_t)(n0 + wave * 32 + 16 + rsub) * K + ksub;
    ushort* lA0 = As + (wave * 32)      * 32;
    ushort* lA1 = As + (wave * 32 + 16) * 32;
    ushort* lB0 = Bs + (wave * 32)      * 32;
    ushort* lB1 = Bs + (wave * 32 + 16) * 32;

    f32x4 acc[4][4];
    #pragma unroll
    for (int i = 0; i < 4; ++i)
        #pragma unroll
        for (int j = 0; j < 4; ++j)
            acc[i][j] = (f32x4){0.f, 0.f, 0.f, 0.f};

    for (int k0 = 0; k0 < K; k0 += 32) {
        __syncthreads();
        gload16(gA0 + k0, lA0);
        gload16(gA1 + k0, lA1);
        gload16(gB0 + k0, lB0);
        gload16(gB1 + k0, lB1);
        __syncthreads();

        short8 af[4], bfr[4];
        #pragma unroll
        for (int i = 0; i < 4; ++i) {
            af[i]  = *(const short8*)&As[(wm + i * 16 + lrow) * 32 + kq];
            bfr[i] = *(const short8*)&Bs[(wn + i * 16 + lrow) * 32 + kq];
        }
        #pragma unroll
        for (int i = 0; i < 4; ++i)
            #pragma unroll
            for (int j = 0; j < 4; ++j)
                acc[i][j] = __builtin_amdgcn_mfma_f32_16x16x32_bf16(
                    af[i], bfr[j], acc[i][j], 0, 0, 0);
    }

    const int rb = m0 + wm + ((lane >> 4) << 2);
    const int cb = n0 + wn + lrow;
    #pragma unroll
    for (int i = 0; i < 4; ++i)
        #pragma unroll
        for (int j = 0; j < 4; ++j)
            #pragma unroll
            for (int r = 0; r < 4; ++r) {
                float v = acc[i][j][r];
                int col = cb + j * 16;
                if (EPI == 1) {
                    v += bias[col];
                    v = (v > 20.f) ? v : log1pf(__expf(v));  // softplus
                }
                C[(size_t)(rb + i * 16 + r) * ldc + col] = v;
            }
}

// ---------------------------------------------------------------------------
// GEMM2 split-K: part[ks] = uconv[:, ks*256:(ks+1)*256] @ W_x[slice].
// ---------------------------------------------------------------------------
#define G2_KSPLIT 8
#define G2_KC     256
#define G2_STAGE  64
__global__ __launch_bounds__(256) void gemm2_splitk(
    const float* __restrict__ A,    // [4096][2048] = uconv
    const float* __restrict__ B,    // [2048][96]   = W_x
    float* __restrict__ part)       // [8][4096][96]
{
    __shared__ float AsT[G2_STAGE][65];
    __shared__ float Bs[G2_STAGE][96];

    const int tid = threadIdx.x;
    const int ks  = blockIdx.x;
    const int m0  = blockIdx.y * 64;
    const int tx  = tid & 15;       // 6 cols each
    const int ty  = tid >> 4;       // 4 rows each

    float acc[4][6] = {};

    for (int st = 0; st < G2_KC / G2_STAGE; ++st) {
        const int k0 = ks * G2_KC + st * G2_STAGE;
        float4 av[4];
        #pragma unroll
        for (int i = 0; i < 4; ++i) {
            int idx = tid + 256 * i;
            int row = idx >> 4, c4 = idx & 15;
            av[i] = *(const float4*)(A + (size_t)(m0 + row) * 2048 + k0 + c4 * 4);
        }
        float4 bv[6];
        #pragma unroll
        for (int i = 0; i < 6; ++i) {
            int idx = tid + 256 * i;
            int row = idx / 24, c4 = idx % 24;
            bv[i] = *(const float4*)(B + (size_t)(k0 + row) * 96 + c4 * 4);
        }
        __syncthreads();
        #pragma unroll
        for (int i = 0; i < 4; ++i) {
            int idx = tid + 256 * i;
            int row = idx >> 4, c4 = idx & 15;
            AsT[c4 * 4 + 0][row] = av[i].x;
            AsT[c4 * 4 + 1][row] = av[i].y;
            AsT[c4 * 4 + 2][row] = av[i].z;
            AsT[c4 * 4 + 3][row] = av[i].w;
        }
        #pragma unroll
        for (int i = 0; i < 6; ++i) {
            int idx = tid + 256 * i;
            int row = idx / 24, c4 = idx % 24;
            *(float4*)&Bs[row][c4 * 4] = bv[i];
        }
        __syncthreads();

        #pragma unroll 8
        for (int kk = 0; kk < G2_STAGE; ++kk) {
            float a[4], b[6];
            #pragma unroll
            for (int r = 0; r < 4; ++r) a[r] = AsT[kk][ty * 4 + r];
            #pragma unroll
            for (int c = 0; c < 6; ++c) b[c] = Bs[kk][tx * 6 + c];
            #pragma unroll
            for (int r = 0; r < 4; ++r)
                #pragma unroll
                for (int c = 0; c < 6; ++c)
                    acc[r][c] += a[r] * b[c];
        }
    }

    float* po = part + (size_t)ks * NTOK * 96;
    #pragma unroll
    for (int r = 0; r < 4; ++r)
        #pragma unroll
        for (int c = 0; c < 6; ++c)
            po[(size_t)(m0 + ty * 4 + r) * 96 + tx * 6 + c] = acc[r][c];
}

__global__ __launch_bounds__(256) void gemm2_reduce(
    const float* __restrict__ part, float* __restrict__ dbc)
{
    int i = (blockIdx.x * 256 + threadIdx.x) * 4;
    float4 s = *(const float4*)(part + i);
    #pragma unroll
    for (int ks = 1; ks < G2_KSPLIT; ++ks) {
        float4 v = *(const float4*)(part + (size_t)ks * NTOK * 96 + i);
        s.x += v.x; s.y += v.y; s.z += v.z; s.w += v.w;
    }
    *(float4*)(dbc + i) = s;
}

// ---------------------------------------------------------------------------
// Causal depthwise conv (K=4) + SiLU.
// ---------------------------------------------------------------------------
__global__ __launch_bounds__(256) void conv_silu_k(
    const float* __restrict__ xz, const float* __restrict__ w_conv,
    const float* __restrict__ b_conv, float* __restrict__ uconv)
{
    int idx   = blockIdx.x * 256 + threadIdx.x;
    int d     = idx & (DIN - 1);
    int token = idx >> 11;
    int t     = token & (L_SEQ - 1);

    float acc = b_conv[d];
    #pragma unroll
    for (int k = 0; k < 4; ++k) {
        int tt = t - 3 + k;
        if (tt >= 0)
            acc += xz[(size_t)(token - 3 + k) * 4096 + d] * w_conv[d * 4 + k];
    }
    float s = acc / (1.f + expf(-acc));
    uconv[(size_t)token * DIN + d] = s;
}

// ---------------------------------------------------------------------------
// Scan pass 1: per (b, dg, chunk) 64-thread (1-wave) block, register-pipelined.
// delta/u live in regs (per-lane private); only B broadcast goes through LDS.
// NO __syncthreads: single wave => LDS ops are wave-order coherent.
// ---------------------------------------------------------------------------
__global__ __launch_bounds__(64) void scan_part1(
    const float* __restrict__ xz,      // delta in cols 0:2048
    const float* __restrict__ uconv,
    const float* __restrict__ dbc,
    const float* __restrict__ A_log,
    float* __restrict__ c_out,         // [2][2048][64][16]
    float* __restrict__ dsum_out)      // [2][2048][64]
{
    int chunk = blockIdx.x & 63;
    int dg    = (blockIdx.x >> 6) & 31;
    int b     = blockIdx.x >> 11;
    int tid   = threadIdx.x;
    int d     = dg * 64 + tid;

    __shared__ float sB[SCHUNK][16];

    // A_log row is contiguous 64 B per lane -> 4x float4
    float Al[NST];
    const float4* pA = (const float4*)(A_log + (size_t)d * NST);
    #pragma unroll
    for (int q = 0; q < 4; ++q) {
        float4 a = pA[q];
        Al[q*4+0] = -__expf(a.x) * LOG2E;
        Al[q*4+1] = -__expf(a.y) * LOG2E;
        Al[q*4+2] = -__expf(a.z) * LOG2E;
        Al[q*4+3] = -__expf(a.w) * LOG2E;
    }

    float h[NST];
    #pragma unroll
    for (int n = 0; n < NST; ++n) h[n] = 0.f;
    float dsum = 0.f;

    const size_t tokbase = (size_t)b * L_SEQ + (size_t)chunk * CLEN;
    const float* pD = xz    + tokbase * 4096 + d;
    const float* pU = uconv + tokbase * 2048 + d;
    const float* pB = dbc   + tokbase * 96 + RRANK;

    float rd[2][SCHUNK], ru[2][SCHUNK], rb[2][2];

    // prologue: stage 0
    #pragma unroll
    for (int i = 0; i < SCHUNK; ++i) {
        rd[0][i] = pD[(size_t)i * 4096];
        ru[0][i] = pU[(size_t)i * 2048];
    }
    #pragma unroll
    for (int i = 0; i < 2; ++i) {
        int e = i * 64 + tid;
        rb[0][i] = pB[(size_t)(e >> 4) * 96 + (e & 15)];
    }

    #pragma unroll
    for (int st = 0; st < NSTAGE; ++st) {
        const int cur = st & 1, nxt = cur ^ 1;
        // commit this stage's B to LDS (in-order DS pipe, no barrier needed)
        #pragma unroll
        for (int i = 0; i < 2; ++i) {
            int e = i * 64 + tid;
            sB[e >> 4][e & 15] = rb[cur][i];
        }
        // prefetch next stage while computing this one
        if (st + 1 < NSTAGE) {
            const size_t to = (size_t)(st + 1) * SCHUNK;
            #pragma unroll
            for (int i = 0; i < SCHUNK; ++i) {
                rd[nxt][i] = pD[(to + i) * 4096];
                ru[nxt][i] = pU[(to + i) * 2048];
            }
            #pragma unroll
            for (int i = 0; i < 2; ++i) {
                int e = i * 64 + tid;
                rb[nxt][i] = pB[(to + (e >> 4)) * 96 + (e & 15)];
            }
        }
        #pragma unroll
        for (int s = 0; s < SCHUNK; ++s) {
            float delta = rd[cur][s];
            float du    = delta * ru[cur][s];
            dsum += delta;
            #pragma unroll
            for (int q = 0; q < 4; ++q) {
                float4 bq = *(const float4*)&sB[s][q * 4];
                h[q*4+0] = h[q*4+0] * fexp2(delta * Al[q*4+0]) + du * bq.x;
                h[q*4+1] = h[q*4+1] * fexp2(delta * Al[q*4+1]) + du * bq.y;
                h[q*4+2] = h[q*4+2] * fexp2(delta * Al[q*4+2]) + du * bq.z;
                h[q*4+3] = h[q*4+3] * fexp2(delta * Al[q*4+3]) + du * bq.w;
            }
        }
    }

    size_t base = (((size_t)b * DIN + d) * GCHUNK + chunk) * NST;
    #pragma unroll
    for (int q = 0; q < 4; ++q)
        *(float4*)&c_out[base + q * 4] = make_float4(h[q*4], h[q*4+1], h[q*4+2], h[q*4+3]);
    dsum_out[((size_t)b * DIN + d) * GCHUNK + chunk] = dsum;
}

// ---------------------------------------------------------------------------
// Pass 2: per (b,d,n) scan the 64 chunk summaries, IN PLACE over c_buf.
// ---------------------------------------------------------------------------
__global__ __launch_bounds__(256) void scan_part2(
    float* __restrict__ cbuf,           // in: c, out: h_start
    const float* __restrict__ dsum_in,  // [2][2048][64]
    const float* __restrict__ A_log)
{
    int idx = blockIdx.x * 256 + threadIdx.x;
    int n   = idx & 15;
    int d   = (idx >> 4) & (DIN - 1);
    int b   = idx >> 15;

    float Al = -__expf(A_log[(size_t)d * NST + n]) * LOG2E;
    size_t cb = ((size_t)b * DIN + d) * GCHUNK;

    float h = 0.f;
    for (int ch = 0; ch < GCHUNK; ++ch) {
        size_t o = (cb + ch) * NST + n;
        float c  = cbuf[o];
        float dA = fexp2(Al * dsum_in[cb + ch]);
        cbuf[o]  = h;
        h = h * dA + c;
    }
}

// ---------------------------------------------------------------------------
// Pass 3: register-pipelined like pass 1, plus z-gate + y output.
// ---------------------------------------------------------------------------
__global__ __launch_bounds__(64) void scan_part3(
    const float* __restrict__ xz,       // delta cols 0:2048, z cols 2048:4096
    float* __restrict__ uconv,          // in: u, out: y
    const float* __restrict__ dbc,
    const float* __restrict__ A_log,
    const float* __restrict__ Dp,
    const float* __restrict__ h_start)
{
    int chunk = blockIdx.x & 63;
    int dg    = (blockIdx.x >> 6) & 31;
    int b     = blockIdx.x >> 11;
    int tid   = threadIdx.x;
    int d     = dg * 64 + tid;

    __shared__ float sBC[SCHUNK][32];   // [s][0:16]=B, [s][16:32]=C

    float Al[NST];
    const float4* pA = (const float4*)(A_log + (size_t)d * NST);
    #pragma unroll
    for (int q = 0; q < 4; ++q) {
        float4 a = pA[q];
        Al[q*4+0] = -__expf(a.x) * LOG2E;
        Al[q*4+1] = -__expf(a.y) * LOG2E;
        Al[q*4+2] = -__expf(a.z) * LOG2E;
        Al[q*4+3] = -__expf(a.w) * LOG2E;
    }
    float Dd = Dp[d];

    float h[NST];
    size_t hb = (((size_t)b * DIN + d) * GCHUNK + chunk) * NST;
    #pragma unroll
    for (int q = 0; q < 4; ++q) {
        float4 v = *(const float4*)&h_start[hb + q * 4];
        h[q*4] = v.x; h[q*4+1] = v.y; h[q*4+2] = v.z; h[q*4+3] = v.w;
    }

    const size_t tokbase = (size_t)b * L_SEQ + (size_t)chunk * CLEN;
    const float* pD = xz    + tokbase * 4096 + d;
    const float* pZ = xz    + tokbase * 4096 + 2048 + d;
    const float* pU = uconv + tokbase * 2048 + d;
    const float* pB = dbc   + tokbase * 96 + RRANK;
    float*       pY = uconv + tokbase * 2048 + d;

    float rd[2][SCHUNK], ru[2][SCHUNK], rz[2][SCHUNK], rb[2][4];

    // prologue: stage 0
    #pragma unroll
    for (int i = 0; i < SCHUNK; ++i) {
        rd[0][i] = pD[(size_t)i * 4096];
        ru[0][i] = pU[(size_t)i * 2048];
        rz[0][i] = pZ[(size_t)i * 4096];
    }
    #pragma unroll
    for (int i = 0; i < 4; ++i) {
        int e = i * 64 + tid;
        rb[0][i] = pB[(size_t)(e >> 5) * 96 + (e & 31)];
    }

    #pragma unroll
    for (int st = 0; st < NSTAGE; ++st) {
        const int cur = st & 1, nxt = cur ^ 1;
        #pragma unroll
        for (int i = 0; i < 4; ++i) {
            int e = i * 64 + tid;
            sBC[e >> 5][e & 31] = rb[cur][i];
        }
        if (st + 1 < NSTAGE) {
            const size_t to = (size_t)(st + 1) * SCHUNK;
            #pragma unroll
            for (int i = 0; i < SCHUNK; ++i) {
                rd[nxt][i] = pD[(to + i) * 4096];
                ru[nxt][i] = pU[(to + i) * 2048];
                rz[nxt][i] = pZ[(to + i) * 4096];
            }
            #pragma unroll
            for (int i = 0; i < 4; ++i) {
                int e = i * 64 + tid;
                rb[nxt][i] = pB[(to + (e >> 5)) * 96 + (e & 31)];
            }
        }
        #pragma unroll
        for (int s = 0; s < SCHUNK; ++s) {
            float delta = rd[cur][s];
            float u     = ru[cur][s];
            float du    = delta * u;
            float y = 0.f;
            #pragma unroll
            for (int q = 0; q < 4; ++q) {
                float4 bq = *(const float4*)&sBC[s][q * 4];
                float4 cq = *(const float4*)&sBC[s][16 + q * 4];
                h[q*4+0] = h[q*4+0] * fexp2(delta * Al[q*4+0]) + du * bq.x; y += h[q*4+0] * cq.x;
                h[q*4+1] = h[q*4+1] * fexp2(delta * Al[q*4+1]) + du * bq.y; y += h[q*4+1] * cq.y;
                h[q*4+2] = h[q*4+2] * fexp2(delta * Al[q*4+2]) + du * bq.z; y += h[q*4+2] * cq.z;
                h[q*4+3] = h[q*4+3] * fexp2(delta * Al[q*4+3]) + du * bq.w; y += h[q*4+3] * cq.w;
            }
            float z  = rz[cur][s];
            float sz = z / (1.f + __expf(-z));
            pY[((size_t)st * SCHUNK + s) * 2048] = (y + u * Dd) * sz;
        }
    }
}

// ---------------------------------------------------------------------------
// LayerNorm over DM + residual.
// ---------------------------------------------------------------------------
__global__ __launch_bounds__(256) void ln_k(
    const float* __restrict__ outpre, const float* __restrict__ x,
    const float* __restrict__ gamma, const float* __restrict__ beta,
    float* __restrict__ out)
{
    int row = blockIdx.x;
    int tid = threadIdx.x;
    const float* rp = outpre + (size_t)row * DMOD;
    float4 v = ((const float4*)rp)[tid];

    float s  = v.x + v.y + v.z + v.w;
    float s2 = v.x * v.x + v.y * v.y + v.z * v.z + v.w * v.w;
    #pragma unroll
    for (int off = 32; off > 0; off >>= 1) {
        s  += __shfl_down(s, off);
        s2 += __shfl_down(s2, off);
    }
    __shared__ float ws[4], ws2[4];
    int wave = tid >> 6, lane = tid & 63;
    if (lane == 0) { ws[wave] = s; ws2[wave] = s2; }
    __syncthreads();
    if (tid == 0) {
        float ts = 0.f, ts2 = 0.f;
        #pragma unroll
        for (int w = 0; w < 4; ++w) { ts += ws[w]; ts2 += ws2[w]; }
        ws[0] = ts; ws2[0] = ts2;
    }
    __syncthreads();
    float mu  = ws[0] * (1.f / DMOD);
    float var = ws2[0] * (1.f / DMOD) - mu * mu;
    float rs  = rsqrtf(var + 1e-5f);

    float4 g  = ((const float4*)gamma)[tid];
    float4 be = ((const float4*)beta)[tid];
    float4 xr = ((const float4*)(x + (size_t)row * DMOD))[tid];
    float4 o;
    o.x = (v.x - mu) * rs * g.x + be.x + xr.x;
    o.y = (v.y - mu) * rs * g.y + be.y + xr.y;
    o.z = (v.z - mu) * rs * g.z + be.z + xr.z;
    o.w = (v.w - mu) * rs * g.w + be.w + xr.w;
    ((float4*)(out + (size_t)row * DMOD))[tid] = o;
}

// ---------------------------------------------------------------------------
extern "C" void kernel_launch(void* const* d_in, const int* in_sizes, int n_in,
                              void* d_out, int out_size, void* d_ws, size_t ws_size,
                              hipStream_t stream)
{
    const float* x      = (const float*)d_in[0];
    const float* W_in   = (const float*)d_in[1];
    const float* w_conv = (const float*)d_in[2];
    const float* b_conv = (const float*)d_in[3];
    const float* W_x    = (const float*)d_in[4];
    const float* W_dt   = (const float*)d_in[5];
    const float* b_dt   = (const float*)d_in[6];
    const float* A_log  = (const float*)d_in[7];
    const float* Dp     = (const float*)d_in[8];
    const float* W_out  = (const float*)d_in[9];
    const float* gamma  = (const float*)d_in[10];
    const float* beta   = (const float*)d_in[11];
    float* out = (float*)d_out;

    char* ws = (char*)d_ws;
    const size_t MB = 1024 * 1024;
    float* xz     = (float*)(ws);                            // [4096][4096] (64 MB)
    float* uconv  = (float*)(ws + 64 * MB);                  // [4096][2048] (32 MB)
    float* dbc    = (float*)(ws + 96 * MB);                  // [4096][96]   (1.5 MB)
    float* dsum   = (float*)(ws + 96 * MB + 1536 * 1024);    // [2][2048][64] (1 MB)
    float* c_buf  = (float*)(ws + 98 * MB + 512 * 1024);     // [2][2048][64][16] (16 MB)
    // pre-GEMM1 (dead after gemm_mfma #1):
    ushort* xb    = (ushort*)(ws + 98 * MB + 512 * 1024);    // [4096][1024] bf16 (8 MB)
    ushort* Wib   = (ushort*)(ws + 106 * MB + 512 * 1024);   // [4096][1024] bf16 (8 MB)
    // GEMM2 phase (dead after reduce):
    float* g2part = (float*)(ws + 98 * MB + 512 * 1024);     // [8][4096][96] (12.6 MB)
    // GEMM3 phase (dead after gemm_mfma #3):
    ushort* dtb   = (ushort*)(ws + 98 * MB + 512 * 1024);    // [4096][64] bf16 (0.5 MB)
    ushort* Wdtb  = (ushort*)(ws + 99 * MB + 512 * 1024);    // [2048][64] bf16 (0.25 MB)
    // post-scan phase (xz dead after scan_part3):
    ushort* yb    = (ushort*)(ws);                           // [4096][2048] bf16 (16 MB)
    ushort* Wob   = (ushort*)(ws + 16 * MB);                 // [1024][2048] bf16 (4 MB)
    float* outpre = (float*)(ws + 32 * MB);                  // [4096][1024] (16 MB)

    dim3 blk(256);

    // 0a. x -> bf16
    cast_bf16_k<<<dim3(NTOK * DMOD / 2048), blk, 0, stream>>>(x, xb);
    // 0b. W_in (1024 x 4096) -> W_in^T bf16 (4096 x 1024)
    tcast_k<<<dim3(4096 / 32, 1024 / 32), blk, 0, stream>>>(W_in, Wib, 1024, 4096);
    // 1. xz = x @ W_in   (MFMA bf16, global_load_lds)
    gemm_mfma<0><<<dim3(4096 / 128, 4096 / 128), blk, 0, stream>>>(
        xb, Wib, xz, 4096, 4096, 1024, 4096, nullptr);
    // 2. u = silu(causal_conv(u)) -> uconv
    conv_silu_k<<<dim3(NTOK * DIN / 256), blk, 0, stream>>>(xz, w_conv, b_conv, uconv);
    // 3. dbc = u @ W_x  (fp32 split-K + reduce)
    gemm2_splitk<<<dim3(G2_KSPLIT, 64), blk, 0, stream>>>(uconv, W_x, g2part);
    gemm2_reduce<<<dim3(NTOK * 96 / 4 / 256), blk, 0, stream>>>(g2part, dbc);
    // 4. delta = softplus(dt @ W_dt + b_dt) -> u-half of xz  (MFMA bf16)
    cast_dt_k<<<dim3(NTOK * 64 / 8 / 256), blk, 0, stream>>>(dbc, dtb);
    tcast_k<<<dim3(2048 / 32, 64 / 32), blk, 0, stream>>>(W_dt, Wdtb, 64, 2048);
    gemm_mfma<1><<<dim3(2048 / 128, 4096 / 128), blk, 0, stream>>>(
        dtb, Wdtb, xz, 4096, 2048, 64, 4096, b_dt);
    // 5. chunked selective scan -> y overwrites uconv
    scan_part1<<<dim3(NBATCH * 32 * GCHUNK), dim3(64), 0, stream>>>(
        xz, uconv, dbc, A_log, c_buf, dsum);
    scan_part2<<<dim3(NBATCH * DIN * NST / 256), blk, 0, stream>>>(
        c_buf, dsum, A_log);
    scan_part3<<<dim3(NBATCH * 32 * GCHUNK), dim3(64), 0, stream>>>(
        xz, uconv, dbc, A_log, Dp, c_buf);
    // 6a. y -> bf16 (xz region is dead now)
    cast_bf16_k<<<dim3(NTOK * DIN / 2048), blk, 0, stream>>>(uconv, yb);
    // 6b. W_out (2048 x 1024) -> W_out^T bf16 (1024 x 2048)
    tcast_k<<<dim3(1024 / 32, 2048 / 32), blk, 0, stream>>>(W_out, Wob, 2048, 1024);
    // 6c. out_pre = y @ W_out  (MFMA bf16)
    gemm_mfma<0><<<dim3(1024 / 128, 4096 / 128), blk, 0, stream>>>(
        yb, Wob, outpre, 4096, 1024, 2048, 1024, nullptr);
    // 7. LayerNorm + residual
    ln_k<<<dim3(NTOK), blk, 0, stream>>>(outpre, x, gamma, beta, out);
}

// Round 7
// 413.024 us; speedup vs baseline: 1.1194x; 1.0273x over previous
//
#include <hip/hip_runtime.h>
#include <math.h>

#define L_SEQ 2048
#define DMOD  1024
#define DIN   2048
#define NBATCH 2
#define NTOK  (NBATCH * L_SEQ)   // 4096 tokens
#define NST   16
#define RRANK 64
#define LOG2E 1.44269504088896f

#define GCHUNK 64                 // chunks along L
#define CLEN   (L_SEQ / GCHUNK)   // 32 steps per chunk
#define SCHUNK 8                  // software-pipeline stage depth
#define NSTAGE (CLEN / SCHUNK)    // 4 stages per chunk

#define G4_KS   4                 // GEMM4 split-K factor
#define G4_KC   (2048 / G4_KS)    // 512 k per slice

typedef __attribute__((ext_vector_type(8))) short  short8;   // 8 bf16
typedef __attribute__((ext_vector_type(4))) float  f32x4;

// round-to-nearest-even fp32 -> bf16
__device__ __forceinline__ ushort f2bf(float f) {
    unsigned u = __float_as_uint(f);
    u += 0x7fffu + ((u >> 16) & 1u);
    return (ushort)(u >> 16);
}

__device__ __forceinline__ float fexp2(float x) {
    return __builtin_amdgcn_exp2f(x);   // raw v_exp_f32
}

// async global->LDS DMA, 16 B per lane; lds dest = wave-uniform base + lane*16
__device__ __forceinline__ void gload16(const ushort* g, ushort* l) {
    __builtin_amdgcn_global_load_lds(
        (const __attribute__((address_space(1))) unsigned int*)g,
        (__attribute__((address_space(3))) unsigned int*)l,
        16, 0, 0);
}

// ---------------------------------------------------------------------------
// Flat cast fp32 -> bf16, 8 elements/thread.
// ---------------------------------------------------------------------------
__global__ __launch_bounds__(256) void cast_bf16_k(
    const float* __restrict__ src, ushort* __restrict__ dst)
{
    int i = (blockIdx.x * 256 + threadIdx.x) * 8;
    float4 a = *(const float4*)(src + i);
    float4 b = *(const float4*)(src + i + 4);
    ushort4 o0 = make_ushort4(f2bf(a.x), f2bf(a.y), f2bf(a.z), f2bf(a.w));
    ushort4 o1 = make_ushort4(f2bf(b.x), f2bf(b.y), f2bf(b.z), f2bf(b.w));
    *(ushort4*)(dst + i)     = o0;
    *(ushort4*)(dst + i + 4) = o1;
}

// ---------------------------------------------------------------------------
// Strided cast: dtb[4096][64] bf16 <- dbc[4096][96] cols 0:64.
// ---------------------------------------------------------------------------
__global__ __launch_bounds__(256) void cast_dt_k(
    const float* __restrict__ dbc, ushort* __restrict__ dtb)
{
    int gid = blockIdx.x * 256 + threadIdx.x;   // 0..32767
    int i   = gid * 8;
    int row = i >> 6, col = i & 63;
    const float* p = dbc + (size_t)row * 96 + col;
    float4 a = *(const float4*)p;
    float4 b = *(const float4*)(p + 4);
    ushort* q = dtb + (size_t)row * 64 + col;
    q[0] = f2bf(a.x); q[1] = f2bf(a.y); q[2] = f2bf(a.z); q[3] = f2bf(a.w);
    q[4] = f2bf(b.x); q[5] = f2bf(b.y); q[6] = f2bf(b.z); q[7] = f2bf(b.w);
}

// ---------------------------------------------------------------------------
// Transpose + cast: src fp32 [R][C] -> dst bf16 [C][R]. 32x32 LDS tile.
// ---------------------------------------------------------------------------
__global__ __launch_bounds__(256) void tcast_k(
    const float* __restrict__ src, ushort* __restrict__ dst, int R, int C)
{
    __shared__ float t[32][33];
    int tx  = threadIdx.x & 31;
    int ty  = threadIdx.x >> 5;        // 0..7
    int c0  = blockIdx.x * 32;
    int r0  = blockIdx.y * 32;
    #pragma unroll
    for (int i = 0; i < 4; ++i)
        t[ty + i * 8][tx] = src[(size_t)(r0 + ty + i * 8) * C + c0 + tx];
    __syncthreads();
    #pragma unroll
    for (int i = 0; i < 4; ++i)
        dst[(size_t)(c0 + ty + i * 8) * R + r0 + tx] = f2bf(t[tx][ty + i * 8]);
}

// ---------------------------------------------------------------------------
// bf16 MFMA GEMM (m97-style): C(M,N) fp32 = A(M,K) @ Bt(N,K)^T.
// 128x128 tile, BK=32, 256 thr = 4 waves, global_load_lds 16B staging.
// EPI=1: softplus(acc + bias[col]).
// ---------------------------------------------------------------------------
template<int EPI>
__global__ __launch_bounds__(256) void gemm_mfma(
    const ushort* __restrict__ A,   // [M][K] bf16
    const ushort* __restrict__ Bt,  // [N][K] bf16
    float* __restrict__ C,          // fp32, leading dim ldc
    int M, int N, int K, int ldc, const float* __restrict__ bias)
{
    __shared__ ushort As[128 * 32];
    __shared__ ushort Bs[128 * 32];

    const int tid  = threadIdx.x;
    const int wave = tid >> 6;
    const int lane = tid & 63;
    const int wm   = (wave & 1) * 64;
    const int wn   = (wave >> 1) * 64;
    const int m0   = blockIdx.y * 128;
    const int n0   = blockIdx.x * 128;

    const int rsub = lane >> 2;         // 0..15
    const int ksub = (lane & 3) * 8;    // 0,8,16,24 halfs
    const int lrow = lane & 15;
    const int kq   = (lane >> 4) * 8;

    const ushort* gA0 = A  + (size_t)(m0 + wave * 32 + rsub)      * K + ksub;
    const ushort* gA1 = A  + (size_t)(m0 + wave * 32 + 16 + rsub) * K + ksub;
    const ushort* gB0 = Bt + (size_t)(n0 + wave * 32 + rsub)      * K + ksub;
    const ushort* gB1 = Bt + (size_t)(n0 + wave * 32 + 16 + rsub) * K + ksub;
    ushort* lA0 = As + (wave * 32)      * 32;
    ushort* lA1 = As + (wave * 32 + 16) * 32;
    ushort* lB0 = Bs + (wave * 32)      * 32;
    ushort* lB1 = Bs + (wave * 32 + 16) * 32;

    f32x4 acc[4][4];
    #pragma unroll
    for (int i = 0; i < 4; ++i)
        #pragma unroll
        for (int j = 0; j < 4; ++j)
            acc[i][j] = (f32x4){0.f, 0.f, 0.f, 0.f};

    for (int k0 = 0; k0 < K; k0 += 32) {
        __syncthreads();
        gload16(gA0 + k0, lA0);
        gload16(gA1 + k0, lA1);
        gload16(gB0 + k0, lB0);
        gload16(gB1 + k0, lB1);
        __syncthreads();

        short8 af[4], bfr[4];
        #pragma unroll
        for (int i = 0; i < 4; ++i) {
            af[i]  = *(const short8*)&As[(wm + i * 16 + lrow) * 32 + kq];
            bfr[i] = *(const short8*)&Bs[(wn + i * 16 + lrow) * 32 + kq];
        }
        #pragma unroll
        for (int i = 0; i < 4; ++i)
            #pragma unroll
            for (int j = 0; j < 4; ++j)
                acc[i][j] = __builtin_amdgcn_mfma_f32_16x16x32_bf16(
                    af[i], bfr[j], acc[i][j], 0, 0, 0);
    }

    const int rb = m0 + wm + ((lane >> 4) << 2);
    const int cb = n0 + wn + lrow;
    #pragma unroll
    for (int i = 0; i < 4; ++i)
        #pragma unroll
        for (int j = 0; j < 4; ++j)
            #pragma unroll
            for (int r = 0; r < 4; ++r) {
                float v = acc[i][j][r];
                int col = cb + j * 16;
                if (EPI == 1) {
                    v += bias[col];
                    v = (v > 20.f) ? v : log1pf(__expf(v));  // softplus
                }
                C[(size_t)(rb + i * 16 + r) * ldc + col] = v;
            }
}

// ---------------------------------------------------------------------------
// GEMM4 split-K MFMA: part[ks] = yb @ Wob^T over k-slice ks.
// Grid (32 m, 8 n, 4 ks), m-major so same-m blocks share an XCD (A-tile L2 reuse).
// M=4096, N=1024, K=2048 fixed.
// ---------------------------------------------------------------------------
__global__ __launch_bounds__(256) void gemm4_splitk(
    const ushort* __restrict__ A,   // [4096][2048] bf16
    const ushort* __restrict__ Bt,  // [1024][2048] bf16
    float* __restrict__ part)       // [4][4096][1024] fp32
{
    __shared__ ushort As[128 * 32];
    __shared__ ushort Bs[128 * 32];

    const int K = 2048;
    const int tid  = threadIdx.x;
    const int wave = tid >> 6;
    const int lane = tid & 63;
    const int wm   = (wave & 1) * 64;
    const int wn   = (wave >> 1) * 64;
    const int m0   = blockIdx.x * 128;       // m-major!
    const int n0   = blockIdx.y * 128;
    const int ks   = blockIdx.z;

    const int rsub = lane >> 2;
    const int ksub = (lane & 3) * 8;
    const int lrow = lane & 15;
    const int kq   = (lane >> 4) * 8;

    const ushort* gA0 = A  + (size_t)(m0 + wave * 32 + rsub)      * K + ksub;
    const ushort* gA1 = A  + (size_t)(m0 + wave * 32 + 16 + rsub) * K + ksub;
    const ushort* gB0 = Bt + (size_t)(n0 + wave * 32 + rsub)      * K + ksub;
    const ushort* gB1 = Bt + (size_t)(n0 + wave * 32 + 16 + rsub) * K + ksub;
    ushort* lA0 = As + (wave * 32)      * 32;
    ushort* lA1 = As + (wave * 32 + 16) * 32;
    ushort* lB0 = Bs + (wave * 32)      * 32;
    ushort* lB1 = Bs + (wave * 32 + 16) * 32;

    f32x4 acc[4][4];
    #pragma unroll
    for (int i = 0; i < 4; ++i)
        #pragma unroll
        for (int j = 0; j < 4; ++j)
            acc[i][j] = (f32x4){0.f, 0.f, 0.f, 0.f};

    const int kbeg = ks * G4_KC, kend = kbeg + G4_KC;
    for (int k0 = kbeg; k0 < kend; k0 += 32) {
        __syncthreads();
        gload16(gA0 + k0, lA0);
        gload16(gA1 + k0, lA1);
        gload16(gB0 + k0, lB0);
        gload16(gB1 + k0, lB1);
        __syncthreads();

        short8 af[4], bfr[4];
        #pragma unroll
        for (int i = 0; i < 4; ++i) {
            af[i]  = *(const short8*)&As[(wm + i * 16 + lrow) * 32 + kq];
            bfr[i] = *(const short8*)&Bs[(wn + i * 16 + lrow) * 32 + kq];
        }
        #pragma unroll
        for (int i = 0; i < 4; ++i)
            #pragma unroll
            for (int j = 0; j < 4; ++j)
                acc[i][j] = __builtin_amdgcn_mfma_f32_16x16x32_bf16(
                    af[i], bfr[j], acc[i][j], 0, 0, 0);
    }

    float* C = part + (size_t)ks * NTOK * DMOD;
    const int rb = m0 + wm + ((lane >> 4) << 2);
    const int cb = n0 + wn + lrow;
    #pragma unroll
    for (int i = 0; i < 4; ++i)
        #pragma unroll
        for (int j = 0; j < 4; ++j)
            #pragma unroll
            for (int r = 0; r < 4; ++r)
                C[(size_t)(rb + i * 16 + r) * DMOD + cb + j * 16] = acc[i][j][r];
}

// ---------------------------------------------------------------------------
// GEMM2 split-K: part[ks] = uconv[:, ks*256:(ks+1)*256] @ W_x[slice].
// ---------------------------------------------------------------------------
#define G2_KSPLIT 8
#define G2_KC     256
#define G2_STAGE  64
__global__ __launch_bounds__(256) void gemm2_splitk(
    const float* __restrict__ A,    // [4096][2048] = uconv
    const float* __restrict__ B,    // [2048][96]   = W_x
    float* __restrict__ part)       // [8][4096][96]
{
    __shared__ float AsT[G2_STAGE][65];
    __shared__ float Bs[G2_STAGE][96];

    const int tid = threadIdx.x;
    const int ks  = blockIdx.x;
    const int m0  = blockIdx.y * 64;
    const int tx  = tid & 15;       // 6 cols each
    const int ty  = tid >> 4;       // 4 rows each

    float acc[4][6] = {};

    for (int st = 0; st < G2_KC / G2_STAGE; ++st) {
        const int k0 = ks * G2_KC + st * G2_STAGE;
        float4 av[4];
        #pragma unroll
        for (int i = 0; i < 4; ++i) {
            int idx = tid + 256 * i;
            int row = idx >> 4, c4 = idx & 15;
            av[i] = *(const float4*)(A + (size_t)(m0 + row) * 2048 + k0 + c4 * 4);
        }
        float4 bv[6];
        #pragma unroll
        for (int i = 0; i < 6; ++i) {
            int idx = tid + 256 * i;
            int row = idx / 24, c4 = idx % 24;
            bv[i] = *(const float4*)(B + (size_t)(k0 + row) * 96 + c4 * 4);
        }
        __syncthreads();
        #pragma unroll
        for (int i = 0; i < 4; ++i) {
            int idx = tid + 256 * i;
            int row = idx >> 4, c4 = idx & 15;
            AsT[c4 * 4 + 0][row] = av[i].x;
            AsT[c4 * 4 + 1][row] = av[i].y;
            AsT[c4 * 4 + 2][row] = av[i].z;
            AsT[c4 * 4 + 3][row] = av[i].w;
        }
        #pragma unroll
        for (int i = 0; i < 6; ++i) {
            int idx = tid + 256 * i;
            int row = idx / 24, c4 = idx % 24;
            *(float4*)&Bs[row][c4 * 4] = bv[i];
        }
        __syncthreads();

        #pragma unroll 8
        for (int kk = 0; kk < G2_STAGE; ++kk) {
            float a[4], b[6];
            #pragma unroll
            for (int r = 0; r < 4; ++r) a[r] = AsT[kk][ty * 4 + r];
            #pragma unroll
            for (int c = 0; c < 6; ++c) b[c] = Bs[kk][tx * 6 + c];
            #pragma unroll
            for (int r = 0; r < 4; ++r)
                #pragma unroll
                for (int c = 0; c < 6; ++c)
                    acc[r][c] += a[r] * b[c];
        }
    }

    float* po = part + (size_t)ks * NTOK * 96;
    #pragma unroll
    for (int r = 0; r < 4; ++r)
        #pragma unroll
        for (int c = 0; c < 6; ++c)
            po[(size_t)(m0 + ty * 4 + r) * 96 + tx * 6 + c] = acc[r][c];
}

__global__ __launch_bounds__(256) void gemm2_reduce(
    const float* __restrict__ part, float* __restrict__ dbc)
{
    int i = (blockIdx.x * 256 + threadIdx.x) * 4;
    float4 s = *(const float4*)(part + i);
    #pragma unroll
    for (int ks = 1; ks < G2_KSPLIT; ++ks) {
        float4 v = *(const float4*)(part + (size_t)ks * NTOK * 96 + i);
        s.x += v.x; s.y += v.y; s.z += v.z; s.w += v.w;
    }
    *(float4*)(dbc + i) = s;
}

// ---------------------------------------------------------------------------
// Causal depthwise conv (K=4) + SiLU.
// ---------------------------------------------------------------------------
__global__ __launch_bounds__(256) void conv_silu_k(
    const float* __restrict__ xz, const float* __restrict__ w_conv,
    const float* __restrict__ b_conv, float* __restrict__ uconv)
{
    int idx   = blockIdx.x * 256 + threadIdx.x;
    int d     = idx & (DIN - 1);
    int token = idx >> 11;
    int t     = token & (L_SEQ - 1);

    float acc = b_conv[d];
    #pragma unroll
    for (int k = 0; k < 4; ++k) {
        int tt = t - 3 + k;
        if (tt >= 0)
            acc += xz[(size_t)(token - 3 + k) * 4096 + d] * w_conv[d * 4 + k];
    }
    float s = acc / (1.f + expf(-acc));
    uconv[(size_t)token * DIN + d] = s;
}

// ---------------------------------------------------------------------------
// Scan pass 1: per (b, dg, chunk) 1-wave block, register-pipelined, no barriers.
// ---------------------------------------------------------------------------
__global__ __launch_bounds__(64) void scan_part1(
    const float* __restrict__ xz,      // delta in cols 0:2048
    const float* __restrict__ uconv,
    const float* __restrict__ dbc,
    const float* __restrict__ A_log,
    float* __restrict__ c_out,         // [2][2048][64][16]
    float* __restrict__ dsum_out)      // [2][2048][64]
{
    int chunk = blockIdx.x & 63;
    int dg    = (blockIdx.x >> 6) & 31;
    int b     = blockIdx.x >> 11;
    int tid   = threadIdx.x;
    int d     = dg * 64 + tid;

    __shared__ float sB[SCHUNK][16];

    float Al[NST];
    const float4* pA = (const float4*)(A_log + (size_t)d * NST);
    #pragma unroll
    for (int q = 0; q < 4; ++q) {
        float4 a = pA[q];
        Al[q*4+0] = -__expf(a.x) * LOG2E;
        Al[q*4+1] = -__expf(a.y) * LOG2E;
        Al[q*4+2] = -__expf(a.z) * LOG2E;
        Al[q*4+3] = -__expf(a.w) * LOG2E;
    }

    float h[NST];
    #pragma unroll
    for (int n = 0; n < NST; ++n) h[n] = 0.f;
    float dsum = 0.f;

    const size_t tokbase = (size_t)b * L_SEQ + (size_t)chunk * CLEN;
    const float* pD = xz    + tokbase * 4096 + d;
    const float* pU = uconv + tokbase * 2048 + d;
    const float* pB = dbc   + tokbase * 96 + RRANK;

    float rd[2][SCHUNK], ru[2][SCHUNK], rb[2][2];

    #pragma unroll
    for (int i = 0; i < SCHUNK; ++i) {
        rd[0][i] = pD[(size_t)i * 4096];
        ru[0][i] = pU[(size_t)i * 2048];
    }
    #pragma unroll
    for (int i = 0; i < 2; ++i) {
        int e = i * 64 + tid;
        rb[0][i] = pB[(size_t)(e >> 4) * 96 + (e & 15)];
    }

    #pragma unroll
    for (int st = 0; st < NSTAGE; ++st) {
        const int cur = st & 1, nxt = cur ^ 1;
        #pragma unroll
        for (int i = 0; i < 2; ++i) {
            int e = i * 64 + tid;
            sB[e >> 4][e & 15] = rb[cur][i];
        }
        if (st + 1 < NSTAGE) {
            const size_t to = (size_t)(st + 1) * SCHUNK;
            #pragma unroll
            for (int i = 0; i < SCHUNK; ++i) {
                rd[nxt][i] = pD[(to + i) * 4096];
                ru[nxt][i] = pU[(to + i) * 2048];
            }
            #pragma unroll
            for (int i = 0; i < 2; ++i) {
                int e = i * 64 + tid;
                rb[nxt][i] = pB[(to + (e >> 4)) * 96 + (e & 15)];
            }
        }
        #pragma unroll
        for (int s = 0; s < SCHUNK; ++s) {
            float delta = rd[cur][s];
            float du    = delta * ru[cur][s];
            dsum += delta;
            #pragma unroll
            for (int q = 0; q < 4; ++q) {
                float4 bq = *(const float4*)&sB[s][q * 4];
                h[q*4+0] = h[q*4+0] * fexp2(delta * Al[q*4+0]) + du * bq.x;
                h[q*4+1] = h[q*4+1] * fexp2(delta * Al[q*4+1]) + du * bq.y;
                h[q*4+2] = h[q*4+2] * fexp2(delta * Al[q*4+2]) + du * bq.z;
                h[q*4+3] = h[q*4+3] * fexp2(delta * Al[q*4+3]) + du * bq.w;
            }
        }
    }

    size_t base = (((size_t)b * DIN + d) * GCHUNK + chunk) * NST;
    #pragma unroll
    for (int q = 0; q < 4; ++q)
        *(float4*)&c_out[base + q * 4] = make_float4(h[q*4], h[q*4+1], h[q*4+2], h[q*4+3]);
    dsum_out[((size_t)b * DIN + d) * GCHUNK + chunk] = dsum;
}

// ---------------------------------------------------------------------------
// Pass 2: per (b,d,n) scan the 64 chunk summaries, IN PLACE over c_buf.
// ---------------------------------------------------------------------------
__global__ __launch_bounds__(256) void scan_part2(
    float* __restrict__ cbuf,           // in: c, out: h_start
    const float* __restrict__ dsum_in,  // [2][2048][64]
    const float* __restrict__ A_log)
{
    int idx = blockIdx.x * 256 + threadIdx.x;
    int n   = idx & 15;
    int d   = (idx >> 4) & (DIN - 1);
    int b   = idx >> 15;

    float Al = -__expf(A_log[(size_t)d * NST + n]) * LOG2E;
    size_t cb = ((size_t)b * DIN + d) * GCHUNK;

    float h = 0.f;
    for (int ch = 0; ch < GCHUNK; ++ch) {
        size_t o = (cb + ch) * NST + n;
        float c  = cbuf[o];
        float dA = fexp2(Al * dsum_in[cb + ch]);
        cbuf[o]  = h;
        h = h * dA + c;
    }
}

// ---------------------------------------------------------------------------
// Pass 3: register-pipelined, z-gate + y output.
// ---------------------------------------------------------------------------
__global__ __launch_bounds__(64) void scan_part3(
    const float* __restrict__ xz,       // delta cols 0:2048, z cols 2048:4096
    float* __restrict__ uconv,          // in: u, out: y
    const float* __restrict__ dbc,
    const float* __restrict__ A_log,
    const float* __restrict__ Dp,
    const float* __restrict__ h_start)
{
    int chunk = blockIdx.x & 63;
    int dg    = (blockIdx.x >> 6) & 31;
    int b     = blockIdx.x >> 11;
    int tid   = threadIdx.x;
    int d     = dg * 64 + tid;

    __shared__ float sBC[SCHUNK][32];   // [s][0:16]=B, [s][16:32]=C

    float Al[NST];
    const float4* pA = (const float4*)(A_log + (size_t)d * NST);
    #pragma unroll
    for (int q = 0; q < 4; ++q) {
        float4 a = pA[q];
        Al[q*4+0] = -__expf(a.x) * LOG2E;
        Al[q*4+1] = -__expf(a.y) * LOG2E;
        Al[q*4+2] = -__expf(a.z) * LOG2E;
        Al[q*4+3] = -__expf(a.w) * LOG2E;
    }
    float Dd = Dp[d];

    float h[NST];
    size_t hb = (((size_t)b * DIN + d) * GCHUNK + chunk) * NST;
    #pragma unroll
    for (int q = 0; q < 4; ++q) {
        float4 v = *(const float4*)&h_start[hb + q * 4];
        h[q*4] = v.x; h[q*4+1] = v.y; h[q*4+2] = v.z; h[q*4+3] = v.w;
    }

    const size_t tokbase = (size_t)b * L_SEQ + (size_t)chunk * CLEN;
    const float* pD = xz    + tokbase * 4096 + d;
    const float* pZ = xz    + tokbase * 4096 + 2048 + d;
    const float* pU = uconv + tokbase * 2048 + d;
    const float* pB = dbc   + tokbase * 96 + RRANK;
    float*       pY = uconv + tokbase * 2048 + d;

    float rd[2][SCHUNK], ru[2][SCHUNK], rz[2][SCHUNK], rb[2][4];

    #pragma unroll
    for (int i = 0; i < SCHUNK; ++i) {
        rd[0][i] = pD[(size_t)i * 4096];
        ru[0][i] = pU[(size_t)i * 2048];
        rz[0][i] = pZ[(size_t)i * 4096];
    }
    #pragma unroll
    for (int i = 0; i < 4; ++i) {
        int e = i * 64 + tid;
        rb[0][i] = pB[(size_t)(e >> 5) * 96 + (e & 31)];
    }

    #pragma unroll
    for (int st = 0; st < NSTAGE; ++st) {
        const int cur = st & 1, nxt = cur ^ 1;
        #pragma unroll
        for (int i = 0; i < 4; ++i) {
            int e = i * 64 + tid;
            sBC[e >> 5][e & 31] = rb[cur][i];
        }
        if (st + 1 < NSTAGE) {
            const size_t to = (size_t)(st + 1) * SCHUNK;
            #pragma unroll
            for (int i = 0; i < SCHUNK; ++i) {
                rd[nxt][i] = pD[(to + i) * 4096];
                ru[nxt][i] = pU[(to + i) * 2048];
                rz[nxt][i] = pZ[(to + i) * 4096];
            }
            #pragma unroll
            for (int i = 0; i < 4; ++i) {
                int e = i * 64 + tid;
                rb[nxt][i] = pB[(to + (e >> 5)) * 96 + (e & 31)];
            }
        }
        #pragma unroll
        for (int s = 0; s < SCHUNK; ++s) {
            float delta = rd[cur][s];
            float u     = ru[cur][s];
            float du    = delta * u;
            float y = 0.f;
            #pragma unroll
            for (int q = 0; q < 4; ++q) {
                float4 bq = *(const float4*)&sBC[s][q * 4];
                float4 cq = *(const float4*)&sBC[s][16 + q * 4];
                h[q*4+0] = h[q*4+0] * fexp2(delta * Al[q*4+0]) + du * bq.x; y += h[q*4+0] * cq.x;
                h[q*4+1] = h[q*4+1] * fexp2(delta * Al[q*4+1]) + du * bq.y; y += h[q*4+1] * cq.y;
                h[q*4+2] = h[q*4+2] * fexp2(delta * Al[q*4+2]) + du * bq.z; y += h[q*4+2] * cq.z;
                h[q*4+3] = h[q*4+3] * fexp2(delta * Al[q*4+3]) + du * bq.w; y += h[q*4+3] * cq.w;
            }
            float z  = rz[cur][s];
            float sz = z / (1.f + __expf(-z));
            pY[((size_t)st * SCHUNK + s) * 2048] = (y + u * Dd) * sz;
        }
    }
}

// ---------------------------------------------------------------------------
// Fused split-K reduce + LayerNorm + residual: out = LN(sum_ks part[ks]) + x.
// One block per row.
// ---------------------------------------------------------------------------
__global__ __launch_bounds__(256) void ln4_k(
    const float* __restrict__ part,  // [4][4096][1024]
    const float* __restrict__ x,
    const float* __restrict__ gamma, const float* __restrict__ beta,
    float* __restrict__ out)
{
    int row = blockIdx.x;
    int tid = threadIdx.x;
    const size_t off = (size_t)row * DMOD + tid * 4;

    float4 v = *(const float4*)(part + off);
    #pragma unroll
    for (int ks = 1; ks < G4_KS; ++ks) {
        float4 p = *(const float4*)(part + (size_t)ks * NTOK * DMOD + off);
        v.x += p.x; v.y += p.y; v.z += p.z; v.w += p.w;
    }

    float s  = v.x + v.y + v.z + v.w;
    float s2 = v.x * v.x + v.y * v.y + v.z * v.z + v.w * v.w;
    #pragma unroll
    for (int off2 = 32; off2 > 0; off2 >>= 1) {
        s  += __shfl_down(s, off2);
        s2 += __shfl_down(s2, off2);
    }
    __shared__ float ws[4], ws2[4];
    int wave = tid >> 6, lane = tid & 63;
    if (lane == 0) { ws[wave] = s; ws2[wave] = s2; }
    __syncthreads();
    if (tid == 0) {
        float ts = 0.f, ts2 = 0.f;
        #pragma unroll
        for (int w = 0; w < 4; ++w) { ts += ws[w]; ts2 += ws2[w]; }
        ws[0] = ts; ws2[0] = ts2;
    }
    __syncthreads();
    float mu  = ws[0] * (1.f / DMOD);
    float var = ws2[0] * (1.f / DMOD) - mu * mu;
    float rs  = rsqrtf(var + 1e-5f);

    float4 g  = ((const float4*)gamma)[tid];
    float4 be = ((const float4*)beta)[tid];
    float4 xr = *(const float4*)(x + off);
    float4 o;
    o.x = (v.x - mu) * rs * g.x + be.x + xr.x;
    o.y = (v.y - mu) * rs * g.y + be.y + xr.y;
    o.z = (v.z - mu) * rs * g.z + be.z + xr.z;
    o.w = (v.w - mu) * rs * g.w + be.w + xr.w;
    *(float4*)(out + off) = o;
}

// ---------------------------------------------------------------------------
extern "C" void kernel_launch(void* const* d_in, const int* in_sizes, int n_in,
                              void* d_out, int out_size, void* d_ws, size_t ws_size,
                              hipStream_t stream)
{
    const float* x      = (const float*)d_in[0];
    const float* W_in   = (const float*)d_in[1];
    const float* w_conv = (const float*)d_in[2];
    const float* b_conv = (const float*)d_in[3];
    const float* W_x    = (const float*)d_in[4];
    const float* W_dt   = (const float*)d_in[5];
    const float* b_dt   = (const float*)d_in[6];
    const float* A_log  = (const float*)d_in[7];
    const float* Dp     = (const float*)d_in[8];
    const float* W_out  = (const float*)d_in[9];
    const float* gamma  = (const float*)d_in[10];
    const float* beta   = (const float*)d_in[11];
    float* out = (float*)d_out;

    char* ws = (char*)d_ws;
    const size_t MB = 1024 * 1024;
    float* xz     = (float*)(ws);                            // [4096][4096] (64 MB)
    float* uconv  = (float*)(ws + 64 * MB);                  // [4096][2048] (32 MB)
    float* dbc    = (float*)(ws + 96 * MB);                  // [4096][96]   (1.5 MB)
    float* dsum   = (float*)(ws + 96 * MB + 1536 * 1024);    // [2][2048][64] (1 MB)
    float* c_buf  = (float*)(ws + 98 * MB + 512 * 1024);     // [2][2048][64][16] (16 MB)
    // pre-GEMM1 (dead after gemm_mfma #1):
    ushort* xb    = (ushort*)(ws + 98 * MB + 512 * 1024);    // [4096][1024] bf16 (8 MB)
    ushort* Wib   = (ushort*)(ws + 106 * MB + 512 * 1024);   // [4096][1024] bf16 (8 MB)
    // GEMM2 phase (dead after reduce):
    float* g2part = (float*)(ws + 98 * MB + 512 * 1024);     // [8][4096][96] (12.6 MB)
    // GEMM3 phase (dead after gemm_mfma #3):
    ushort* dtb   = (ushort*)(ws + 98 * MB + 512 * 1024);    // [4096][64] bf16 (0.5 MB)
    ushort* Wdtb  = (ushort*)(ws + 99 * MB + 512 * 1024);    // [2048][64] bf16 (0.25 MB)
    // post-scan phase (xz dead after scan_part3; uconv dead after y-cast):
    ushort* yb    = (ushort*)(ws);                           // [4096][2048] bf16 (16 MB)
    ushort* Wob   = (ushort*)(ws + 16 * MB);                 // [1024][2048] bf16 (4 MB)
    float* g4part = (float*)(ws + 32 * MB);                  // [4][4096][1024] (64 MB, 32-96)

    dim3 blk(256);

    // 0a. x -> bf16
    cast_bf16_k<<<dim3(NTOK * DMOD / 2048), blk, 0, stream>>>(x, xb);
    // 0b. W_in (1024 x 4096) -> W_in^T bf16 (4096 x 1024)
    tcast_k<<<dim3(4096 / 32, 1024 / 32), blk, 0, stream>>>(W_in, Wib, 1024, 4096);
    // 1. xz = x @ W_in   (MFMA bf16, global_load_lds)
    gemm_mfma<0><<<dim3(4096 / 128, 4096 / 128), blk, 0, stream>>>(
        xb, Wib, xz, 4096, 4096, 1024, 4096, nullptr);
    // 2. u = silu(causal_conv(u)) -> uconv
    conv_silu_k<<<dim3(NTOK * DIN / 256), blk, 0, stream>>>(xz, w_conv, b_conv, uconv);
    // 3. dbc = u @ W_x  (fp32 split-K + reduce)
    gemm2_splitk<<<dim3(G2_KSPLIT, 64), blk, 0, stream>>>(uconv, W_x, g2part);
    gemm2_reduce<<<dim3(NTOK * 96 / 4 / 256), blk, 0, stream>>>(g2part, dbc);
    // 4. delta = softplus(dt @ W_dt + b_dt) -> u-half of xz  (MFMA bf16)
    cast_dt_k<<<dim3(NTOK * 64 / 8 / 256), blk, 0, stream>>>(dbc, dtb);
    tcast_k<<<dim3(2048 / 32, 64 / 32), blk, 0, stream>>>(W_dt, Wdtb, 64, 2048);
    gemm_mfma<1><<<dim3(2048 / 128, 4096 / 128), blk, 0, stream>>>(
        dtb, Wdtb, xz, 4096, 2048, 64, 4096, b_dt);
    // 5. chunked selective scan -> y overwrites uconv
    scan_part1<<<dim3(NBATCH * 32 * GCHUNK), dim3(64), 0, stream>>>(
        xz, uconv, dbc, A_log, c_buf, dsum);
    scan_part2<<<dim3(NBATCH * DIN * NST / 256), blk, 0, stream>>>(
        c_buf, dsum, A_log);
    scan_part3<<<dim3(NBATCH * 32 * GCHUNK), dim3(64), 0, stream>>>(
        xz, uconv, dbc, A_log, Dp, c_buf);
    // 6a. y -> bf16 (xz region dead after scan_part3)
    cast_bf16_k<<<dim3(NTOK * DIN / 2048), blk, 0, stream>>>(uconv, yb);
    // 6b. W_out (2048 x 1024) -> W_out^T bf16 (1024 x 2048)
    tcast_k<<<dim3(1024 / 32, 2048 / 32), blk, 0, stream>>>(W_out, Wob, 2048, 1024);
    // 6c. split-K MFMA: partials (uconv dead after 6a)
    gemm4_splitk<<<dim3(32, 8, G4_KS), blk, 0, stream>>>(yb, Wob, g4part);
    // 7. fused reduce + LayerNorm + residual
    ln4_k<<<dim3(NTOK), blk, 0, stream>>>(g4part, x, gamma, beta, out);
}

// Round 8
// 400.086 us; speedup vs baseline: 1.1556x; 1.0323x over previous
//
#include <hip/hip_runtime.h>
#include <math.h>

#define L_SEQ 2048
#define DMOD  1024
#define DIN   2048
#define NBATCH 2
#define NTOK  (NBATCH * L_SEQ)   // 4096 tokens
#define NST   16
#define RRANK 64
#define LOG2E 1.44269504088896f

#define GCHUNK 64                 // chunks along L
#define CLEN   (L_SEQ / GCHUNK)   // 32 steps per chunk
#define SCHUNK 8                  // software-pipeline stage depth
#define NSTAGE (CLEN / SCHUNK)    // 4 stages per chunk

#define G4_KS   4                 // GEMM4 split-K factor
#define G4_KC   (2048 / G4_KS)    // 512 k per slice

#define BK 64                     // MFMA GEMM K-tile (128 B LDS rows, 8 granules)

typedef __attribute__((ext_vector_type(8))) short  short8;   // 8 bf16
typedef __attribute__((ext_vector_type(4))) float  f32x4;

// round-to-nearest-even fp32 -> bf16
__device__ __forceinline__ ushort f2bf(float f) {
    unsigned u = __float_as_uint(f);
    u += 0x7fffu + ((u >> 16) & 1u);
    return (ushort)(u >> 16);
}
__device__ __forceinline__ float bf2f(ushort u) {
    return __uint_as_float(((unsigned)u) << 16);
}

__device__ __forceinline__ float fexp2(float x) {
    return __builtin_amdgcn_exp2f(x);
}

// async global->LDS DMA, 16 B per lane; lds dest = wave-uniform base + lane*16
__device__ __forceinline__ void gload16(const ushort* g, ushort* l) {
    __builtin_amdgcn_global_load_lds(
        (const __attribute__((address_space(1))) unsigned int*)g,
        (__attribute__((address_space(3))) unsigned int*)l,
        16, 0, 0);
}

// ---------------------------------------------------------------------------
// Flat cast fp32 -> bf16, 8 elements/thread.
// ---------------------------------------------------------------------------
__global__ __launch_bounds__(256) void cast_bf16_k(
    const float* __restrict__ src, ushort* __restrict__ dst)
{
    int i = (blockIdx.x * 256 + threadIdx.x) * 8;
    float4 a = *(const float4*)(src + i);
    float4 b = *(const float4*)(src + i + 4);
    ushort4 o0 = make_ushort4(f2bf(a.x), f2bf(a.y), f2bf(a.z), f2bf(a.w));
    ushort4 o1 = make_ushort4(f2bf(b.x), f2bf(b.y), f2bf(b.z), f2bf(b.w));
    *(ushort4*)(dst + i)     = o0;
    *(ushort4*)(dst + i + 4) = o1;
}

// ---------------------------------------------------------------------------
// Strided cast: dtb[4096][64] bf16 <- dbc[4096][96] cols 0:64.
// ---------------------------------------------------------------------------
__global__ __launch_bounds__(256) void cast_dt_k(
    const float* __restrict__ dbc, ushort* __restrict__ dtb)
{
    int gid = blockIdx.x * 256 + threadIdx.x;   // 0..32767
    int i   = gid * 8;
    int row = i >> 6, col = i & 63;
    const float* p = dbc + (size_t)row * 96 + col;
    float4 a = *(const float4*)p;
    float4 b = *(const float4*)(p + 4);
    ushort* q = dtb + (size_t)row * 64 + col;
    q[0] = f2bf(a.x); q[1] = f2bf(a.y); q[2] = f2bf(a.z); q[3] = f2bf(a.w);
    q[4] = f2bf(b.x); q[5] = f2bf(b.y); q[6] = f2bf(b.z); q[7] = f2bf(b.w);
}

// ---------------------------------------------------------------------------
// Transpose + cast: src fp32 [R][C] -> dst bf16 [C][R]. 32x32 LDS tile.
// ---------------------------------------------------------------------------
__global__ __launch_bounds__(256) void tcast_k(
    const float* __restrict__ src, ushort* __restrict__ dst, int R, int C)
{
    __shared__ float t[32][33];
    int tx  = threadIdx.x & 31;
    int ty  = threadIdx.x >> 5;        // 0..7
    int c0  = blockIdx.x * 32;
    int r0  = blockIdx.y * 32;
    #pragma unroll
    for (int i = 0; i < 4; ++i)
        t[ty + i * 8][tx] = src[(size_t)(r0 + ty + i * 8) * C + c0 + tx];
    __syncthreads();
    #pragma unroll
    for (int i = 0; i < 4; ++i)
        dst[(size_t)(c0 + ty + i * 8) * R + r0 + tx] = f2bf(t[tx][ty + i * 8]);
}

// ---------------------------------------------------------------------------
// bf16 MFMA GEMM, BK=64 + XOR-swizzled LDS (conflict-free b128 reads):
// global 16B-granule g of row r lives at LDS slot g ^ (r&7); the swizzle is
// applied to the DMA *source* address so the LDS dest stays linear (m104).
// C(M,N) fp32 = A(M,K) @ Bt(N,K)^T. 128x128 tile, 256 thr = 4 waves.
// EPI=1: softplus(acc + bias[col]). Requires K%64==0.
// ---------------------------------------------------------------------------
template<int EPI>
__global__ __launch_bounds__(256) void gemm_mfma(
    const ushort* __restrict__ A,   // [M][K] bf16
    const ushort* __restrict__ Bt,  // [N][K] bf16
    float* __restrict__ C,          // fp32, leading dim ldc
    int M, int N, int K, int ldc, const float* __restrict__ bias)
{
    __shared__ ushort As[128 * BK];
    __shared__ ushort Bs[128 * BK];

    const int tid  = threadIdx.x;
    const int wave = tid >> 6;
    const int lane = tid & 63;
    const int wm   = (wave & 1) * 64;
    const int wn   = (wave >> 1) * 64;
    const int m0   = blockIdx.y * 128;
    const int n0   = blockIdx.x * 128;

    // staging: wave stages rows [wave*32, +32) of A and B, 4 passes x 8 rows
    const int srow = lane >> 3;                  // row within pass (= row&7)
    const int sg   = (lane & 7) ^ srow;          // swizzled source granule
    const ushort* gA = A  + (size_t)(m0 + wave * 32 + srow) * K + sg * 8;
    const ushort* gB = Bt + (size_t)(n0 + wave * 32 + srow) * K + sg * 8;
    ushort* lA = As + (wave * 32) * BK;
    ushort* lB = Bs + (wave * 32) * BK;

    const int lrow = lane & 15;
    const int g0   = lane >> 4;                       // 0..3
    const int sw0  = ((g0)     ^ (lrow & 7)) * 8;     // k 0..31 frag offset
    const int sw1  = ((g0 + 4) ^ (lrow & 7)) * 8;     // k 32..63 frag offset

    f32x4 acc[4][4];
    #pragma unroll
    for (int i = 0; i < 4; ++i)
        #pragma unroll
        for (int j = 0; j < 4; ++j)
            acc[i][j] = (f32x4){0.f, 0.f, 0.f, 0.f};

    for (int k0 = 0; k0 < K; k0 += BK) {
        __syncthreads();
        #pragma unroll
        for (int p = 0; p < 4; ++p) {
            gload16(gA + k0 + (size_t)p * 8 * K, lA + p * 8 * BK);
            gload16(gB + k0 + (size_t)p * 8 * K, lB + p * 8 * BK);
        }
        __syncthreads();

        short8 af[4], bfr[4];
        #pragma unroll
        for (int i = 0; i < 4; ++i) {
            af[i]  = *(const short8*)&As[(wm + i * 16 + lrow) * BK + sw0];
            bfr[i] = *(const short8*)&Bs[(wn + i * 16 + lrow) * BK + sw0];
        }
        #pragma unroll
        for (int i = 0; i < 4; ++i)
            #pragma unroll
            for (int j = 0; j < 4; ++j)
                acc[i][j] = __builtin_amdgcn_mfma_f32_16x16x32_bf16(
                    af[i], bfr[j], acc[i][j], 0, 0, 0);
        #pragma unroll
        for (int i = 0; i < 4; ++i) {
            af[i]  = *(const short8*)&As[(wm + i * 16 + lrow) * BK + sw1];
            bfr[i] = *(const short8*)&Bs[(wn + i * 16 + lrow) * BK + sw1];
        }
        #pragma unroll
        for (int i = 0; i < 4; ++i)
            #pragma unroll
            for (int j = 0; j < 4; ++j)
                acc[i][j] = __builtin_amdgcn_mfma_f32_16x16x32_bf16(
                    af[i], bfr[j], acc[i][j], 0, 0, 0);
    }

    // C/D layout: col = lane&15, row = (lane>>4)*4 + reg
    const int rb = m0 + wm + ((lane >> 4) << 2);
    const int cb = n0 + wn + lrow;
    #pragma unroll
    for (int i = 0; i < 4; ++i)
        #pragma unroll
        for (int j = 0; j < 4; ++j)
            #pragma unroll
            for (int r = 0; r < 4; ++r) {
                float v = acc[i][j][r];
                int col = cb + j * 16;
                if (EPI == 1) {
                    v += bias[col];
                    v = (v > 20.f) ? v : log1pf(__expf(v));  // softplus
                }
                C[(size_t)(rb + i * 16 + r) * ldc + col] = v;
            }
}

// ---------------------------------------------------------------------------
// GEMM4 split-K MFMA (BK=64 + swizzle): part[ks] (bf16) = yb @ Wob^T slice.
// Grid (32 m, 8 n, 4 ks), m-major for A-tile L2 reuse. M=4096,N=1024,K=2048.
// ---------------------------------------------------------------------------
__global__ __launch_bounds__(256) void gemm4_splitk(
    const ushort* __restrict__ A,   // [4096][2048] bf16
    const ushort* __restrict__ Bt,  // [1024][2048] bf16
    ushort* __restrict__ part)      // [4][4096][1024] bf16
{
    __shared__ ushort As[128 * BK];
    __shared__ ushort Bs[128 * BK];

    const int K = 2048;
    const int tid  = threadIdx.x;
    const int wave = tid >> 6;
    const int lane = tid & 63;
    const int wm   = (wave & 1) * 64;
    const int wn   = (wave >> 1) * 64;
    const int m0   = blockIdx.x * 128;       // m-major!
    const int n0   = blockIdx.y * 128;
    const int ks   = blockIdx.z;

    const int srow = lane >> 3;
    const int sg   = (lane & 7) ^ srow;
    const ushort* gA = A  + (size_t)(m0 + wave * 32 + srow) * K + sg * 8;
    const ushort* gB = Bt + (size_t)(n0 + wave * 32 + srow) * K + sg * 8;
    ushort* lA = As + (wave * 32) * BK;
    ushort* lB = Bs + (wave * 32) * BK;

    const int lrow = lane & 15;
    const int g0   = lane >> 4;
    const int sw0  = ((g0)     ^ (lrow & 7)) * 8;
    const int sw1  = ((g0 + 4) ^ (lrow & 7)) * 8;

    f32x4 acc[4][4];
    #pragma unroll
    for (int i = 0; i < 4; ++i)
        #pragma unroll
        for (int j = 0; j < 4; ++j)
            acc[i][j] = (f32x4){0.f, 0.f, 0.f, 0.f};

    const int kbeg = ks * G4_KC, kend = kbeg + G4_KC;
    for (int k0 = kbeg; k0 < kend; k0 += BK) {
        __syncthreads();
        #pragma unroll
        for (int p = 0; p < 4; ++p) {
            gload16(gA + k0 + (size_t)p * 8 * K, lA + p * 8 * BK);
            gload16(gB + k0 + (size_t)p * 8 * K, lB + p * 8 * BK);
        }
        __syncthreads();

        short8 af[4], bfr[4];
        #pragma unroll
        for (int i = 0; i < 4; ++i) {
            af[i]  = *(const short8*)&As[(wm + i * 16 + lrow) * BK + sw0];
            bfr[i] = *(const short8*)&Bs[(wn + i * 16 + lrow) * BK + sw0];
        }
        #pragma unroll
        for (int i = 0; i < 4; ++i)
            #pragma unroll
            for (int j = 0; j < 4; ++j)
                acc[i][j] = __builtin_amdgcn_mfma_f32_16x16x32_bf16(
                    af[i], bfr[j], acc[i][j], 0, 0, 0);
        #pragma unroll
        for (int i = 0; i < 4; ++i) {
            af[i]  = *(const short8*)&As[(wm + i * 16 + lrow) * BK + sw1];
            bfr[i] = *(const short8*)&Bs[(wn + i * 16 + lrow) * BK + sw1];
        }
        #pragma unroll
        for (int i = 0; i < 4; ++i)
            #pragma unroll
            for (int j = 0; j < 4; ++j)
                acc[i][j] = __builtin_amdgcn_mfma_f32_16x16x32_bf16(
                    af[i], bfr[j], acc[i][j], 0, 0, 0);
    }

    ushort* Cp = part + (size_t)ks * NTOK * DMOD;
    const int rb = m0 + wm + ((lane >> 4) << 2);
    const int cb = n0 + wn + lrow;
    #pragma unroll
    for (int i = 0; i < 4; ++i)
        #pragma unroll
        for (int j = 0; j < 4; ++j)
            #pragma unroll
            for (int r = 0; r < 4; ++r)
                Cp[(size_t)(rb + i * 16 + r) * DMOD + cb + j * 16] = f2bf(acc[i][j][r]);
}

// ---------------------------------------------------------------------------
// GEMM2 split-K: part[ks] = uconv[:, ks*256:(ks+1)*256] @ W_x[slice].
// ---------------------------------------------------------------------------
#define G2_KSPLIT 8
#define G2_KC     256
#define G2_STAGE  64
__global__ __launch_bounds__(256) void gemm2_splitk(
    const float* __restrict__ A,    // [4096][2048] = uconv
    const float* __restrict__ B,    // [2048][96]   = W_x
    float* __restrict__ part)       // [8][4096][96]
{
    __shared__ float AsT[G2_STAGE][65];
    __shared__ float Bs[G2_STAGE][96];

    const int tid = threadIdx.x;
    const int ks  = blockIdx.x;
    const int m0  = blockIdx.y * 64;
    const int tx  = tid & 15;       // 6 cols each
    const int ty  = tid >> 4;       // 4 rows each

    float acc[4][6] = {};

    for (int st = 0; st < G2_KC / G2_STAGE; ++st) {
        const int k0 = ks * G2_KC + st * G2_STAGE;
        float4 av[4];
        #pragma unroll
        for (int i = 0; i < 4; ++i) {
            int idx = tid + 256 * i;
            int row = idx >> 4, c4 = idx & 15;
            av[i] = *(const float4*)(A + (size_t)(m0 + row) * 2048 + k0 + c4 * 4);
        }
        float4 bv[6];
        #pragma unroll
        for (int i = 0; i < 6; ++i) {
            int idx = tid + 256 * i;
            int row = idx / 24, c4 = idx % 24;
            bv[i] = *(const float4*)(B + (size_t)(k0 + row) * 96 + c4 * 4);
        }
        __syncthreads();
        #pragma unroll
        for (int i = 0; i < 4; ++i) {
            int idx = tid + 256 * i;
            int row = idx >> 4, c4 = idx & 15;
            AsT[c4 * 4 + 0][row] = av[i].x;
            AsT[c4 * 4 + 1][row] = av[i].y;
            AsT[c4 * 4 + 2][row] = av[i].z;
            AsT[c4 * 4 + 3][row] = av[i].w;
        }
        #pragma unroll
        for (int i = 0; i < 6; ++i) {
            int idx = tid + 256 * i;
            int row = idx / 24, c4 = idx % 24;
            *(float4*)&Bs[row][c4 * 4] = bv[i];
        }
        __syncthreads();

        #pragma unroll 8
        for (int kk = 0; kk < G2_STAGE; ++kk) {
            float a[4], b[6];
            #pragma unroll
            for (int r = 0; r < 4; ++r) a[r] = AsT[kk][ty * 4 + r];
            #pragma unroll
            for (int c = 0; c < 6; ++c) b[c] = Bs[kk][tx * 6 + c];
            #pragma unroll
            for (int r = 0; r < 4; ++r)
                #pragma unroll
                for (int c = 0; c < 6; ++c)
                    acc[r][c] += a[r] * b[c];
        }
    }

    float* po = part + (size_t)ks * NTOK * 96;
    #pragma unroll
    for (int r = 0; r < 4; ++r)
        #pragma unroll
        for (int c = 0; c < 6; ++c)
            po[(size_t)(m0 + ty * 4 + r) * 96 + tx * 6 + c] = acc[r][c];
}

__global__ __launch_bounds__(256) void gemm2_reduce(
    const float* __restrict__ part, float* __restrict__ dbc)
{
    int i = (blockIdx.x * 256 + threadIdx.x) * 4;
    float4 s = *(const float4*)(part + i);
    #pragma unroll
    for (int ks = 1; ks < G2_KSPLIT; ++ks) {
        float4 v = *(const float4*)(part + (size_t)ks * NTOK * 96 + i);
        s.x += v.x; s.y += v.y; s.z += v.z; s.w += v.w;
    }
    *(float4*)(dbc + i) = s;
}

// ---------------------------------------------------------------------------
// Causal depthwise conv (K=4) + SiLU.
// ---------------------------------------------------------------------------
__global__ __launch_bounds__(256) void conv_silu_k(
    const float* __restrict__ xz, const float* __restrict__ w_conv,
    const float* __restrict__ b_conv, float* __restrict__ uconv)
{
    int idx   = blockIdx.x * 256 + threadIdx.x;
    int d     = idx & (DIN - 1);
    int token = idx >> 11;
    int t     = token & (L_SEQ - 1);

    float acc = b_conv[d];
    #pragma unroll
    for (int k = 0; k < 4; ++k) {
        int tt = t - 3 + k;
        if (tt >= 0)
            acc += xz[(size_t)(token - 3 + k) * 4096 + d] * w_conv[d * 4 + k];
    }
    float s = acc / (1.f + expf(-acc));
    uconv[(size_t)token * DIN + d] = s;
}

// ---------------------------------------------------------------------------
// Scan pass 1: per (b, dg, chunk) 1-wave block, register-pipelined, no barriers.
// ---------------------------------------------------------------------------
__global__ __launch_bounds__(64) void scan_part1(
    const float* __restrict__ xz,      // delta in cols 0:2048
    const float* __restrict__ uconv,
    const float* __restrict__ dbc,
    const float* __restrict__ A_log,
    float* __restrict__ c_out,         // [2][2048][64][16]
    float* __restrict__ dsum_out)      // [2][2048][64]
{
    int chunk = blockIdx.x & 63;
    int dg    = (blockIdx.x >> 6) & 31;
    int b     = blockIdx.x >> 11;
    int tid   = threadIdx.x;
    int d     = dg * 64 + tid;

    __shared__ float sB[SCHUNK][16];

    float Al[NST];
    const float4* pA = (const float4*)(A_log + (size_t)d * NST);
    #pragma unroll
    for (int q = 0; q < 4; ++q) {
        float4 a = pA[q];
        Al[q*4+0] = -__expf(a.x) * LOG2E;
        Al[q*4+1] = -__expf(a.y) * LOG2E;
        Al[q*4+2] = -__expf(a.z) * LOG2E;
        Al[q*4+3] = -__expf(a.w) * LOG2E;
    }

    float h[NST];
    #pragma unroll
    for (int n = 0; n < NST; ++n) h[n] = 0.f;
    float dsum = 0.f;

    const size_t tokbase = (size_t)b * L_SEQ + (size_t)chunk * CLEN;
    const float* pD = xz    + tokbase * 4096 + d;
    const float* pU = uconv + tokbase * 2048 + d;
    const float* pB = dbc   + tokbase * 96 + RRANK;

    float rd[2][SCHUNK], ru[2][SCHUNK], rb[2][2];

    #pragma unroll
    for (int i = 0; i < SCHUNK; ++i) {
        rd[0][i] = pD[(size_t)i * 4096];
        ru[0][i] = pU[(size_t)i * 2048];
    }
    #pragma unroll
    for (int i = 0; i < 2; ++i) {
        int e = i * 64 + tid;
        rb[0][i] = pB[(size_t)(e >> 4) * 96 + (e & 15)];
    }

    #pragma unroll
    for (int st = 0; st < NSTAGE; ++st) {
        const int cur = st & 1, nxt = cur ^ 1;
        #pragma unroll
        for (int i = 0; i < 2; ++i) {
            int e = i * 64 + tid;
            sB[e >> 4][e & 15] = rb[cur][i];
        }
        if (st + 1 < NSTAGE) {
            const size_t to = (size_t)(st + 1) * SCHUNK;
            #pragma unroll
            for (int i = 0; i < SCHUNK; ++i) {
                rd[nxt][i] = pD[(to + i) * 4096];
                ru[nxt][i] = pU[(to + i) * 2048];
            }
            #pragma unroll
            for (int i = 0; i < 2; ++i) {
                int e = i * 64 + tid;
                rb[nxt][i] = pB[(to + (e >> 4)) * 96 + (e & 15)];
            }
        }
        #pragma unroll
        for (int s = 0; s < SCHUNK; ++s) {
            float delta = rd[cur][s];
            float du    = delta * ru[cur][s];
            dsum += delta;
            #pragma unroll
            for (int q = 0; q < 4; ++q) {
                float4 bq = *(const float4*)&sB[s][q * 4];
                h[q*4+0] = h[q*4+0] * fexp2(delta * Al[q*4+0]) + du * bq.x;
                h[q*4+1] = h[q*4+1] * fexp2(delta * Al[q*4+1]) + du * bq.y;
                h[q*4+2] = h[q*4+2] * fexp2(delta * Al[q*4+2]) + du * bq.z;
                h[q*4+3] = h[q*4+3] * fexp2(delta * Al[q*4+3]) + du * bq.w;
            }
        }
    }

    size_t base = (((size_t)b * DIN + d) * GCHUNK + chunk) * NST;
    #pragma unroll
    for (int q = 0; q < 4; ++q)
        *(float4*)&c_out[base + q * 4] = make_float4(h[q*4], h[q*4+1], h[q*4+2], h[q*4+3]);
    dsum_out[((size_t)b * DIN + d) * GCHUNK + chunk] = dsum;
}

// ---------------------------------------------------------------------------
// Pass 2: per (b,d,n) scan the 64 chunk summaries, IN PLACE over c_buf.
// ---------------------------------------------------------------------------
__global__ __launch_bounds__(256) void scan_part2(
    float* __restrict__ cbuf,           // in: c, out: h_start
    const float* __restrict__ dsum_in,  // [2][2048][64]
    const float* __restrict__ A_log)
{
    int idx = blockIdx.x * 256 + threadIdx.x;
    int n   = idx & 15;
    int d   = (idx >> 4) & (DIN - 1);
    int b   = idx >> 15;

    float Al = -__expf(A_log[(size_t)d * NST + n]) * LOG2E;
    size_t cb = ((size_t)b * DIN + d) * GCHUNK;

    float h = 0.f;
    for (int ch = 0; ch < GCHUNK; ++ch) {
        size_t o = (cb + ch) * NST + n;
        float c  = cbuf[o];
        float dA = fexp2(Al * dsum_in[cb + ch]);
        cbuf[o]  = h;
        h = h * dA + c;
    }
}

// ---------------------------------------------------------------------------
// Pass 3: register-pipelined, z-gate + y output.
// ---------------------------------------------------------------------------
__global__ __launch_bounds__(64) void scan_part3(
    const float* __restrict__ xz,       // delta cols 0:2048, z cols 2048:4096
    float* __restrict__ uconv,          // in: u, out: y
    const float* __restrict__ dbc,
    const float* __restrict__ A_log,
    const float* __restrict__ Dp,
    const float* __restrict__ h_start)
{
    int chunk = blockIdx.x & 63;
    int dg    = (blockIdx.x >> 6) & 31;
    int b     = blockIdx.x >> 11;
    int tid   = threadIdx.x;
    int d     = dg * 64 + tid;

    __shared__ float sBC[SCHUNK][32];   // [s][0:16]=B, [s][16:32]=C

    float Al[NST];
    const float4* pA = (const float4*)(A_log + (size_t)d * NST);
    #pragma unroll
    for (int q = 0; q < 4; ++q) {
        float4 a = pA[q];
        Al[q*4+0] = -__expf(a.x) * LOG2E;
        Al[q*4+1] = -__expf(a.y) * LOG2E;
        Al[q*4+2] = -__expf(a.z) * LOG2E;
        Al[q*4+3] = -__expf(a.w) * LOG2E;
    }
    float Dd = Dp[d];

    float h[NST];
    size_t hb = (((size_t)b * DIN + d) * GCHUNK + chunk) * NST;
    #pragma unroll
    for (int q = 0; q < 4; ++q) {
        float4 v = *(const float4*)&h_start[hb + q * 4];
        h[q*4] = v.x; h[q*4+1] = v.y; h[q*4+2] = v.z; h[q*4+3] = v.w;
    }

    const size_t tokbase = (size_t)b * L_SEQ + (size_t)chunk * CLEN;
    const float* pD = xz    + tokbase * 4096 + d;
    const float* pZ = xz    + tokbase * 4096 + 2048 + d;
    const float* pU = uconv + tokbase * 2048 + d;
    const float* pB = dbc   + tokbase * 96 + RRANK;
    float*       pY = uconv + tokbase * 2048 + d;

    float rd[2][SCHUNK], ru[2][SCHUNK], rz[2][SCHUNK], rb[2][4];

    #pragma unroll
    for (int i = 0; i < SCHUNK; ++i) {
        rd[0][i] = pD[(size_t)i * 4096];
        ru[0][i] = pU[(size_t)i * 2048];
        rz[0][i] = pZ[(size_t)i * 4096];
    }
    #pragma unroll
    for (int i = 0; i < 4; ++i) {
        int e = i * 64 + tid;
        rb[0][i] = pB[(size_t)(e >> 5) * 96 + (e & 31)];
    }

    #pragma unroll
    for (int st = 0; st < NSTAGE; ++st) {
        const int cur = st & 1, nxt = cur ^ 1;
        #pragma unroll
        for (int i = 0; i < 4; ++i) {
            int e = i * 64 + tid;
            sBC[e >> 5][e & 31] = rb[cur][i];
        }
        if (st + 1 < NSTAGE) {
            const size_t to = (size_t)(st + 1) * SCHUNK;
            #pragma unroll
            for (int i = 0; i < SCHUNK; ++i) {
                rd[nxt][i] = pD[(to + i) * 4096];
                ru[nxt][i] = pU[(to + i) * 2048];
                rz[nxt][i] = pZ[(to + i) * 4096];
            }
            #pragma unroll
            for (int i = 0; i < 4; ++i) {
                int e = i * 64 + tid;
                rb[nxt][i] = pB[(to + (e >> 5)) * 96 + (e & 31)];
            }
        }
        #pragma unroll
        for (int s = 0; s < SCHUNK; ++s) {
            float delta = rd[cur][s];
            float u     = ru[cur][s];
            float du    = delta * u;
            float y = 0.f;
            #pragma unroll
            for (int q = 0; q < 4; ++q) {
                float4 bq = *(const float4*)&sBC[s][q * 4];
                float4 cq = *(const float4*)&sBC[s][16 + q * 4];
                h[q*4+0] = h[q*4+0] * fexp2(delta * Al[q*4+0]) + du * bq.x; y += h[q*4+0] * cq.x;
                h[q*4+1] = h[q*4+1] * fexp2(delta * Al[q*4+1]) + du * bq.y; y += h[q*4+1] * cq.y;
                h[q*4+2] = h[q*4+2] * fexp2(delta * Al[q*4+2]) + du * bq.z; y += h[q*4+2] * cq.z;
                h[q*4+3] = h[q*4+3] * fexp2(delta * Al[q*4+3]) + du * bq.w; y += h[q*4+3] * cq.w;
            }
            float z  = rz[cur][s];
            float sz = z / (1.f + __expf(-z));
            pY[((size_t)st * SCHUNK + s) * 2048] = (y + u * Dd) * sz;
        }
    }
}

// ---------------------------------------------------------------------------
// Fused split-K reduce (bf16 partials) + LayerNorm + residual.
// ---------------------------------------------------------------------------
__global__ __launch_bounds__(256) void ln4_k(
    const ushort* __restrict__ part,  // [4][4096][1024] bf16
    const float* __restrict__ x,
    const float* __restrict__ gamma, const float* __restrict__ beta,
    float* __restrict__ out)
{
    int row = blockIdx.x;
    int tid = threadIdx.x;
    const size_t off = (size_t)row * DMOD + tid * 4;

    float4 v = {0.f, 0.f, 0.f, 0.f};
    #pragma unroll
    for (int ks = 0; ks < G4_KS; ++ks) {
        ushort4 p = *(const ushort4*)(part + (size_t)ks * NTOK * DMOD + off);
        v.x += bf2f(p.x); v.y += bf2f(p.y); v.z += bf2f(p.z); v.w += bf2f(p.w);
    }

    float s  = v.x + v.y + v.z + v.w;
    float s2 = v.x * v.x + v.y * v.y + v.z * v.z + v.w * v.w;
    #pragma unroll
    for (int off2 = 32; off2 > 0; off2 >>= 1) {
        s  += __shfl_down(s, off2);
        s2 += __shfl_down(s2, off2);
    }
    __shared__ float ws[4], ws2[4];
    int wave = tid >> 6, lane = tid & 63;
    if (lane == 0) { ws[wave] = s; ws2[wave] = s2; }
    __syncthreads();
    if (tid == 0) {
        float ts = 0.f, ts2 = 0.f;
        #pragma unroll
        for (int w = 0; w < 4; ++w) { ts += ws[w]; ts2 += ws2[w]; }
        ws[0] = ts; ws2[0] = ts2;
    }
    __syncthreads();
    float mu  = ws[0] * (1.f / DMOD);
    float var = ws2[0] * (1.f / DMOD) - mu * mu;
    float rs  = rsqrtf(var + 1e-5f);

    float4 g  = ((const float4*)gamma)[tid];
    float4 be = ((const float4*)beta)[tid];
    float4 xr = *(const float4*)(x + off);
    float4 o;
    o.x = (v.x - mu) * rs * g.x + be.x + xr.x;
    o.y = (v.y - mu) * rs * g.y + be.y + xr.y;
    o.z = (v.z - mu) * rs * g.z + be.z + xr.z;
    o.w = (v.w - mu) * rs * g.w + be.w + xr.w;
    *(float4*)(out + off) = o;
}

// ---------------------------------------------------------------------------
extern "C" void kernel_launch(void* const* d_in, const int* in_sizes, int n_in,
                              void* d_out, int out_size, void* d_ws, size_t ws_size,
                              hipStream_t stream)
{
    const float* x      = (const float*)d_in[0];
    const float* W_in   = (const float*)d_in[1];
    const float* w_conv = (const float*)d_in[2];
    const float* b_conv = (const float*)d_in[3];
    const float* W_x    = (const float*)d_in[4];
    const float* W_dt   = (const float*)d_in[5];
    const float* b_dt   = (const float*)d_in[6];
    const float* A_log  = (const float*)d_in[7];
    const float* Dp     = (const float*)d_in[8];
    const float* W_out  = (const float*)d_in[9];
    const float* gamma  = (const float*)d_in[10];
    const float* beta   = (const float*)d_in[11];
    float* out = (float*)d_out;

    char* ws = (char*)d_ws;
    const size_t MB = 1024 * 1024;
    float* xz     = (float*)(ws);                            // [4096][4096] (64 MB)
    float* uconv  = (float*)(ws + 64 * MB);                  // [4096][2048] (32 MB)
    float* dbc    = (float*)(ws + 96 * MB);                  // [4096][96]   (1.5 MB)
    float* dsum   = (float*)(ws + 96 * MB + 1536 * 1024);    // [2][2048][64] (1 MB)
    float* c_buf  = (float*)(ws + 98 * MB + 512 * 1024);     // [2][2048][64][16] (16 MB)
    // pre-GEMM1 (dead after gemm_mfma #1):
    ushort* xb    = (ushort*)(ws + 98 * MB + 512 * 1024);    // [4096][1024] bf16 (8 MB)
    ushort* Wib   = (ushort*)(ws + 106 * MB + 512 * 1024);   // [4096][1024] bf16 (8 MB)
    // GEMM2 phase (dead after reduce):
    float* g2part = (float*)(ws + 98 * MB + 512 * 1024);     // [8][4096][96] (12.6 MB)
    // GEMM3 phase (dead after gemm_mfma #3):
    ushort* dtb   = (ushort*)(ws + 98 * MB + 512 * 1024);    // [4096][64] bf16 (0.5 MB)
    ushort* Wdtb  = (ushort*)(ws + 99 * MB + 512 * 1024);    // [2048][64] bf16 (0.25 MB)
    // post-scan phase (xz dead after scan_part3; uconv dead after y-cast):
    ushort* yb    = (ushort*)(ws);                           // [4096][2048] bf16 (16 MB)
    ushort* Wob   = (ushort*)(ws + 16 * MB);                 // [1024][2048] bf16 (4 MB)
    ushort* g4part = (ushort*)(ws + 32 * MB);                // [4][4096][1024] bf16 (32 MB)

    dim3 blk(256);

    // 0a. x -> bf16
    cast_bf16_k<<<dim3(NTOK * DMOD / 2048), blk, 0, stream>>>(x, xb);
    // 0b. W_in (1024 x 4096) -> W_in^T bf16 (4096 x 1024)
    tcast_k<<<dim3(4096 / 32, 1024 / 32), blk, 0, stream>>>(W_in, Wib, 1024, 4096);
    // 1. xz = x @ W_in   (MFMA bf16, BK=64 swizzled)
    gemm_mfma<0><<<dim3(4096 / 128, 4096 / 128), blk, 0, stream>>>(
        xb, Wib, xz, 4096, 4096, 1024, 4096, nullptr);
    // 2. u = silu(causal_conv(u)) -> uconv
    conv_silu_k<<<dim3(NTOK * DIN / 256), blk, 0, stream>>>(xz, w_conv, b_conv, uconv);
    // 3. dbc = u @ W_x  (fp32 split-K + reduce)
    gemm2_splitk<<<dim3(G2_KSPLIT, 64), blk, 0, stream>>>(uconv, W_x, g2part);
    gemm2_reduce<<<dim3(NTOK * 96 / 4 / 256), blk, 0, stream>>>(g2part, dbc);
    // 4. delta = softplus(dt @ W_dt + b_dt) -> u-half of xz  (MFMA bf16)
    cast_dt_k<<<dim3(NTOK * 64 / 8 / 256), blk, 0, stream>>>(dbc, dtb);
    tcast_k<<<dim3(2048 / 32, 64 / 32), blk, 0, stream>>>(W_dt, Wdtb, 64, 2048);
    gemm_mfma<1><<<dim3(2048 / 128, 4096 / 128), blk, 0, stream>>>(
        dtb, Wdtb, xz, 4096, 2048, 64, 4096, b_dt);
    // 5. chunked selective scan -> y overwrites uconv
    scan_part1<<<dim3(NBATCH * 32 * GCHUNK), dim3(64), 0, stream>>>(
        xz, uconv, dbc, A_log, c_buf, dsum);
    scan_part2<<<dim3(NBATCH * DIN * NST / 256), blk, 0, stream>>>(
        c_buf, dsum, A_log);
    scan_part3<<<dim3(NBATCH * 32 * GCHUNK), dim3(64), 0, stream>>>(
        xz, uconv, dbc, A_log, Dp, c_buf);
    // 6a. y -> bf16 (xz region dead after scan_part3)
    cast_bf16_k<<<dim3(NTOK * DIN / 2048), blk, 0, stream>>>(uconv, yb);
    // 6b. W_out (2048 x 1024) -> W_out^T bf16 (1024 x 2048)
    tcast_k<<<dim3(1024 / 32, 2048 / 32), blk, 0, stream>>>(W_out, Wob, 2048, 1024);
    // 6c. split-K MFMA: bf16 partials (uconv dead after 6a)
    gemm4_splitk<<<dim3(32, 8, G4_KS), blk, 0, stream>>>(yb, Wob, g4part);
    // 7. fused reduce + LayerNorm + residual
    ln4_k<<<dim3(NTOK), blk, 0, stream>>>(g4part, x, gamma, beta, out);
}

// Round 9
// 398.382 us; speedup vs baseline: 1.1605x; 1.0043x over previous
//
#include <hip/hip_runtime.h>
#include <math.h>

#define L_SEQ 2048
#define DMOD  1024
#define DIN   2048
#define NBATCH 2
#define NTOK  (NBATCH * L_SEQ)   // 4096 tokens
#define NST   16
#define RRANK 64
#define LOG2E 1.44269504088896f

#define GCHUNK 64                 // chunks along L
#define CLEN   (L_SEQ / GCHUNK)   // 32 steps per chunk
#define SCHUNK 8                  // software-pipeline stage depth
#define NSTAGE (CLEN / SCHUNK)    // 4 stages per chunk

#define G4_KS   4                 // GEMM4 split-K factor
#define G4_KC   (2048 / G4_KS)    // 512 k per slice

typedef __attribute__((ext_vector_type(8))) short  short8;   // 8 bf16
typedef __attribute__((ext_vector_type(4))) float  f32x4;

// round-to-nearest-even fp32 -> bf16
__device__ __forceinline__ ushort f2bf(float f) {
    unsigned u = __float_as_uint(f);
    u += 0x7fffu + ((u >> 16) & 1u);
    return (ushort)(u >> 16);
}
__device__ __forceinline__ float bf2f(ushort u) {
    return __uint_as_float(((unsigned)u) << 16);
}
__device__ __forceinline__ float fexp2(float x) {
    return __builtin_amdgcn_exp2f(x);
}

// async global->LDS DMA, 16 B per lane; lds dest = wave-uniform base + lane*16
__device__ __forceinline__ void gload16(const ushort* g, ushort* l) {
    __builtin_amdgcn_global_load_lds(
        (const __attribute__((address_space(1))) unsigned int*)g,
        (__attribute__((address_space(3))) unsigned int*)l,
        16, 0, 0);
}

// ---------------------------------------------------------------------------
// Device helpers: flat cast (2048 elems/block) and 32x32 transpose-cast tile.
// ---------------------------------------------------------------------------
__device__ __forceinline__ void cast_body(
    const float* __restrict__ src, ushort* __restrict__ dst, int bid, int tid)
{
    int i = (bid * 256 + tid) * 8;
    float4 a = *(const float4*)(src + i);
    float4 b = *(const float4*)(src + i + 4);
    ushort4 o0 = make_ushort4(f2bf(a.x), f2bf(a.y), f2bf(a.z), f2bf(a.w));
    ushort4 o1 = make_ushort4(f2bf(b.x), f2bf(b.y), f2bf(b.z), f2bf(b.w));
    *(ushort4*)(dst + i)     = o0;
    *(ushort4*)(dst + i + 4) = o1;
}

__device__ __forceinline__ void tcast_body(
    const float* __restrict__ src, ushort* __restrict__ dst,
    int R, int C, int bx, int by, int tid)
{
    __shared__ float t[32][33];
    int tx = tid & 31;
    int ty = tid >> 5;          // 0..7
    int c0 = bx * 32;
    int r0 = by * 32;
    #pragma unroll
    for (int i = 0; i < 4; ++i)
        t[ty + i * 8][tx] = src[(size_t)(r0 + ty + i * 8) * C + c0 + tx];
    __syncthreads();
    #pragma unroll
    for (int i = 0; i < 4; ++i)
        dst[(size_t)(c0 + ty + i * 8) * R + r0 + tx] = f2bf(t[tx][ty + i * 8]);
}

// ---------------------------------------------------------------------------
// Fused prep: blocks [0,2048) cast x->xb; [2048,6144) W_in^T->Wib;
// [6144,6272) W_dt^T->Wdtb.
// ---------------------------------------------------------------------------
__global__ __launch_bounds__(256) void prep_k(
    const float* __restrict__ x, const float* __restrict__ W_in,
    const float* __restrict__ W_dt,
    ushort* __restrict__ xb, ushort* __restrict__ Wib, ushort* __restrict__ Wdtb)
{
    int bid = blockIdx.x, tid = threadIdx.x;
    if (bid < 2048) {
        cast_body(x, xb, bid, tid);
    } else if (bid < 6144) {
        int t = bid - 2048;                 // W_in: R=1024, C=4096
        tcast_body(W_in, Wib, 1024, 4096, t & 127, t >> 7, tid);
    } else {
        int t = bid - 6144;                 // W_dt: R=64, C=2048
        tcast_body(W_dt, Wdtb, 64, 2048, t & 63, t >> 6, tid);
    }
}

// ---------------------------------------------------------------------------
// Fused post-scan: blocks [0,4096) cast y(uconv)->yb; [4096,6144) W_out^T->Wob.
// ---------------------------------------------------------------------------
__global__ __launch_bounds__(256) void post_k(
    const float* __restrict__ uconv, const float* __restrict__ W_out,
    ushort* __restrict__ yb, ushort* __restrict__ Wob)
{
    int bid = blockIdx.x, tid = threadIdx.x;
    if (bid < 4096) {
        cast_body(uconv, yb, bid, tid);
    } else {
        int t = bid - 4096;                 // W_out: R=2048, C=1024
        tcast_body(W_out, Wob, 2048, 1024, t & 31, t >> 5, tid);
    }
}

// ---------------------------------------------------------------------------
// bf16 MFMA GEMM, BK=32 + XOR-swizzled LDS.
// Swizzle: granule g of row r lives at LDS slot g ^ ((r>>1)&3); applied to the
// DMA *source* address so LDS dest stays linear (m104). Read phases then hit
// 8 distinct bank-groups x 2 lanes = 2-way aliasing = free (m136).
// C(M,N) fp32 = A(M,K) @ Bt(N,K)^T. 128x128 tile, 256 thr = 4 waves.
// EPI=1: softplus(acc + bias[col]). Requires K%32==0.
// ---------------------------------------------------------------------------
template<int EPI>
__global__ __launch_bounds__(256) void gemm_mfma(
    const ushort* __restrict__ A,   // [M][K] bf16
    const ushort* __restrict__ Bt,  // [N][K] bf16
    float* __restrict__ C,          // fp32, leading dim ldc
    int M, int N, int K, int ldc, const float* __restrict__ bias)
{
    __shared__ ushort As[128 * 32];   // 8 KB
    __shared__ ushort Bs[128 * 32];

    const int tid  = threadIdx.x;
    const int wave = tid >> 6;
    const int lane = tid & 63;
    const int wm   = (wave & 1) * 64;
    const int wn   = (wave >> 1) * 64;
    const int m0   = blockIdx.y * 128;
    const int n0   = blockIdx.x * 128;

    // staging: per wave 32 rows of A + 32 of B (2 gload16 each)
    const int srow = lane >> 2;                       // 0..15
    const int sg   = (lane & 3) ^ ((srow >> 1) & 3);  // swizzled src granule
    const ushort* gA0 = A  + (size_t)(m0 + wave * 32 + srow)      * K + sg * 8;
    const ushort* gA1 = A  + (size_t)(m0 + wave * 32 + 16 + srow) * K + sg * 8;
    const ushort* gB0 = Bt + (size_t)(n0 + wave * 32 + srow)      * K + sg * 8;
    const ushort* gB1 = Bt + (size_t)(n0 + wave * 32 + 16 + srow) * K + sg * 8;
    ushort* lA0 = As + (wave * 32)      * 32;
    ushort* lA1 = As + (wave * 32 + 16) * 32;
    ushort* lB0 = Bs + (wave * 32)      * 32;
    ushort* lB1 = Bs + (wave * 32 + 16) * 32;

    const int lrow = lane & 15;
    const int swr  = ((lane >> 4) ^ ((lrow >> 1) & 3)) * 8;  // frag slot offset

    f32x4 acc[4][4];
    #pragma unroll
    for (int i = 0; i < 4; ++i)
        #pragma unroll
        for (int j = 0; j < 4; ++j)
            acc[i][j] = (f32x4){0.f, 0.f, 0.f, 0.f};

    for (int k0 = 0; k0 < K; k0 += 32) {
        __syncthreads();
        gload16(gA0 + k0, lA0);
        gload16(gA1 + k0, lA1);
        gload16(gB0 + k0, lB0);
        gload16(gB1 + k0, lB1);
        __syncthreads();

        short8 af[4], bfr[4];
        #pragma unroll
        for (int i = 0; i < 4; ++i) {
            af[i]  = *(const short8*)&As[(wm + i * 16 + lrow) * 32 + swr];
            bfr[i] = *(const short8*)&Bs[(wn + i * 16 + lrow) * 32 + swr];
        }
        #pragma unroll
        for (int i = 0; i < 4; ++i)
            #pragma unroll
            for (int j = 0; j < 4; ++j)
                acc[i][j] = __builtin_amdgcn_mfma_f32_16x16x32_bf16(
                    af[i], bfr[j], acc[i][j], 0, 0, 0);
    }

    // C/D layout: col = lane&15, row = (lane>>4)*4 + reg
    const int rb = m0 + wm + ((lane >> 4) << 2);
    const int cb = n0 + wn + lrow;
    #pragma unroll
    for (int i = 0; i < 4; ++i)
        #pragma unroll
        for (int j = 0; j < 4; ++j)
            #pragma unroll
            for (int r = 0; r < 4; ++r) {
                float v = acc[i][j][r];
                int col = cb + j * 16;
                if (EPI == 1) {
                    v += bias[col];
                    v = (v > 20.f) ? v : log1pf(__expf(v));  // softplus
                }
                C[(size_t)(rb + i * 16 + r) * ldc + col] = v;
            }
}

// ---------------------------------------------------------------------------
// GEMM4 split-K MFMA (BK=32 + swizzle): part[ks] (bf16) = yb @ Wob^T slice.
// Grid (32 m, 8 n, 4 ks), m-major for A-tile L2 reuse. M=4096,N=1024,K=2048.
// ---------------------------------------------------------------------------
__global__ __launch_bounds__(256) void gemm4_splitk(
    const ushort* __restrict__ A,   // [4096][2048] bf16
    const ushort* __restrict__ Bt,  // [1024][2048] bf16
    ushort* __restrict__ part)      // [4][4096][1024] bf16
{
    __shared__ ushort As[128 * 32];
    __shared__ ushort Bs[128 * 32];

    const int K = 2048;
    const int tid  = threadIdx.x;
    const int wave = tid >> 6;
    const int lane = tid & 63;
    const int wm   = (wave & 1) * 64;
    const int wn   = (wave >> 1) * 64;
    const int m0   = blockIdx.x * 128;       // m-major!
    const int n0   = blockIdx.y * 128;
    const int ks   = blockIdx.z;

    const int srow = lane >> 2;
    const int sg   = (lane & 3) ^ ((srow >> 1) & 3);
    const ushort* gA0 = A  + (size_t)(m0 + wave * 32 + srow)      * K + sg * 8;
    const ushort* gA1 = A  + (size_t)(m0 + wave * 32 + 16 + srow) * K + sg * 8;
    const ushort* gB0 = Bt + (size_t)(n0 + wave * 32 + srow)      * K + sg * 8;
    const ushort* gB1 = Bt + (size_t)(n0 + wave * 32 + 16 + srow) * K + sg * 8;
    ushort* lA0 = As + (wave * 32)      * 32;
    ushort* lA1 = As + (wave * 32 + 16) * 32;
    ushort* lB0 = Bs + (wave * 32)      * 32;
    ushort* lB1 = Bs + (wave * 32 + 16) * 32;

    const int lrow = lane & 15;
    const int swr  = ((lane >> 4) ^ ((lrow >> 1) & 3)) * 8;

    f32x4 acc[4][4];
    #pragma unroll
    for (int i = 0; i < 4; ++i)
        #pragma unroll
        for (int j = 0; j < 4; ++j)
            acc[i][j] = (f32x4){0.f, 0.f, 0.f, 0.f};

    const int kbeg = ks * G4_KC, kend = kbeg + G4_KC;
    for (int k0 = kbeg; k0 < kend; k0 += 32) {
        __syncthreads();
        gload16(gA0 + k0, lA0);
        gload16(gA1 + k0, lA1);
        gload16(gB0 + k0, lB0);
        gload16(gB1 + k0, lB1);
        __syncthreads();

        short8 af[4], bfr[4];
        #pragma unroll
        for (int i = 0; i < 4; ++i) {
            af[i]  = *(const short8*)&As[(wm + i * 16 + lrow) * 32 + swr];
            bfr[i] = *(const short8*)&Bs[(wn + i * 16 + lrow) * 32 + swr];
        }
        #pragma unroll
        for (int i = 0; i < 4; ++i)
            #pragma unroll
            for (int j = 0; j < 4; ++j)
                acc[i][j] = __builtin_amdgcn_mfma_f32_16x16x32_bf16(
                    af[i], bfr[j], acc[i][j], 0, 0, 0);
    }

    ushort* Cp = part + (size_t)ks * NTOK * DMOD;
    const int rb = m0 + wm + ((lane >> 4) << 2);
    const int cb = n0 + wn + lrow;
    #pragma unroll
    for (int i = 0; i < 4; ++i)
        #pragma unroll
        for (int j = 0; j < 4; ++j)
            #pragma unroll
            for (int r = 0; r < 4; ++r)
                Cp[(size_t)(rb + i * 16 + r) * DMOD + cb + j * 16] = f2bf(acc[i][j][r]);
}

// ---------------------------------------------------------------------------
// GEMM2 split-K: part[ks] = uconv[:, ks*256:(ks+1)*256] @ W_x[slice].
// ---------------------------------------------------------------------------
#define G2_KSPLIT 8
#define G2_KC     256
#define G2_STAGE  64
__global__ __launch_bounds__(256) void gemm2_splitk(
    const float* __restrict__ A,    // [4096][2048] = uconv
    const float* __restrict__ B,    // [2048][96]   = W_x
    float* __restrict__ part)       // [8][4096][96]
{
    __shared__ float AsT[G2_STAGE][65];
    __shared__ float Bs[G2_STAGE][96];

    const int tid = threadIdx.x;
    const int ks  = blockIdx.x;
    const int m0  = blockIdx.y * 64;
    const int tx  = tid & 15;       // 6 cols each
    const int ty  = tid >> 4;       // 4 rows each

    float acc[4][6] = {};

    for (int st = 0; st < G2_KC / G2_STAGE; ++st) {
        const int k0 = ks * G2_KC + st * G2_STAGE;
        float4 av[4];
        #pragma unroll
        for (int i = 0; i < 4; ++i) {
            int idx = tid + 256 * i;
            int row = idx >> 4, c4 = idx & 15;
            av[i] = *(const float4*)(A + (size_t)(m0 + row) * 2048 + k0 + c4 * 4);
        }
        float4 bv[6];
        #pragma unroll
        for (int i = 0; i < 6; ++i) {
            int idx = tid + 256 * i;
            int row = idx / 24, c4 = idx % 24;
            bv[i] = *(const float4*)(B + (size_t)(k0 + row) * 96 + c4 * 4);
        }
        __syncthreads();
        #pragma unroll
        for (int i = 0; i < 4; ++i) {
            int idx = tid + 256 * i;
            int row = idx >> 4, c4 = idx & 15;
            AsT[c4 * 4 + 0][row] = av[i].x;
            AsT[c4 * 4 + 1][row] = av[i].y;
            AsT[c4 * 4 + 2][row] = av[i].z;
            AsT[c4 * 4 + 3][row] = av[i].w;
        }
        #pragma unroll
        for (int i = 0; i < 6; ++i) {
            int idx = tid + 256 * i;
            int row = idx / 24, c4 = idx % 24;
            *(float4*)&Bs[row][c4 * 4] = bv[i];
        }
        __syncthreads();

        #pragma unroll 8
        for (int kk = 0; kk < G2_STAGE; ++kk) {
            float a[4], b[6];
            #pragma unroll
            for (int r = 0; r < 4; ++r) a[r] = AsT[kk][ty * 4 + r];
            #pragma unroll
            for (int c = 0; c < 6; ++c) b[c] = Bs[kk][tx * 6 + c];
            #pragma unroll
            for (int r = 0; r < 4; ++r)
                #pragma unroll
                for (int c = 0; c < 6; ++c)
                    acc[r][c] += a[r] * b[c];
        }
    }

    float* po = part + (size_t)ks * NTOK * 96;
    #pragma unroll
    for (int r = 0; r < 4; ++r)
        #pragma unroll
        for (int c = 0; c < 6; ++c)
            po[(size_t)(m0 + ty * 4 + r) * 96 + tx * 6 + c] = acc[r][c];
}

// ---------------------------------------------------------------------------
// GEMM2 reduce + fused dt bf16 cast (cols 0:64 of dbc -> dtb).
// ---------------------------------------------------------------------------
__global__ __launch_bounds__(256) void gemm2_reduce_dt(
    const float* __restrict__ part, float* __restrict__ dbc,
    ushort* __restrict__ dtb)
{
    int i = (blockIdx.x * 256 + threadIdx.x) * 4;
    float4 s = *(const float4*)(part + i);
    #pragma unroll
    for (int ks = 1; ks < G2_KSPLIT; ++ks) {
        float4 v = *(const float4*)(part + (size_t)ks * NTOK * 96 + i);
        s.x += v.x; s.y += v.y; s.z += v.z; s.w += v.w;
    }
    *(float4*)(dbc + i) = s;
    int col = i % 96;
    if (col < RRANK) {
        int row = i / 96;
        ushort* q = dtb + (size_t)row * RRANK + col;
        q[0] = f2bf(s.x); q[1] = f2bf(s.y); q[2] = f2bf(s.z); q[3] = f2bf(s.w);
    }
}

// ---------------------------------------------------------------------------
// Causal depthwise conv (K=4) + SiLU.
// ---------------------------------------------------------------------------
__global__ __launch_bounds__(256) void conv_silu_k(
    const float* __restrict__ xz, const float* __restrict__ w_conv,
    const float* __restrict__ b_conv, float* __restrict__ uconv)
{
    int idx   = blockIdx.x * 256 + threadIdx.x;
    int d     = idx & (DIN - 1);
    int token = idx >> 11;
    int t     = token & (L_SEQ - 1);

    float acc = b_conv[d];
    #pragma unroll
    for (int k = 0; k < 4; ++k) {
        int tt = t - 3 + k;
        if (tt >= 0)
            acc += xz[(size_t)(token - 3 + k) * 4096 + d] * w_conv[d * 4 + k];
    }
    float s = acc / (1.f + expf(-acc));
    uconv[(size_t)token * DIN + d] = s;
}

// ---------------------------------------------------------------------------
// Scan pass 1: per (b, dg, chunk) 1-wave block, register-pipelined, no barriers.
// ---------------------------------------------------------------------------
__global__ __launch_bounds__(64) void scan_part1(
    const float* __restrict__ xz,      // delta in cols 0:2048
    const float* __restrict__ uconv,
    const float* __restrict__ dbc,
    const float* __restrict__ A_log,
    float* __restrict__ c_out,         // [2][2048][64][16]
    float* __restrict__ dsum_out)      // [2][2048][64]
{
    int chunk = blockIdx.x & 63;
    int dg    = (blockIdx.x >> 6) & 31;
    int b     = blockIdx.x >> 11;
    int tid   = threadIdx.x;
    int d     = dg * 64 + tid;

    __shared__ float sB[SCHUNK][16];

    float Al[NST];
    const float4* pA = (const float4*)(A_log + (size_t)d * NST);
    #pragma unroll
    for (int q = 0; q < 4; ++q) {
        float4 a = pA[q];
        Al[q*4+0] = -__expf(a.x) * LOG2E;
        Al[q*4+1] = -__expf(a.y) * LOG2E;
        Al[q*4+2] = -__expf(a.z) * LOG2E;
        Al[q*4+3] = -__expf(a.w) * LOG2E;
    }

    float h[NST];
    #pragma unroll
    for (int n = 0; n < NST; ++n) h[n] = 0.f;
    float dsum = 0.f;

    const size_t tokbase = (size_t)b * L_SEQ + (size_t)chunk * CLEN;
    const float* pD = xz    + tokbase * 4096 + d;
    const float* pU = uconv + tokbase * 2048 + d;
    const float* pB = dbc   + tokbase * 96 + RRANK;

    float rd[2][SCHUNK], ru[2][SCHUNK], rb[2][2];

    #pragma unroll
    for (int i = 0; i < SCHUNK; ++i) {
        rd[0][i] = pD[(size_t)i * 4096];
        ru[0][i] = pU[(size_t)i * 2048];
    }
    #pragma unroll
    for (int i = 0; i < 2; ++i) {
        int e = i * 64 + tid;
        rb[0][i] = pB[(size_t)(e >> 4) * 96 + (e & 15)];
    }

    #pragma unroll
    for (int st = 0; st < NSTAGE; ++st) {
        const int cur = st & 1, nxt = cur ^ 1;
        #pragma unroll
        for (int i = 0; i < 2; ++i) {
            int e = i * 64 + tid;
            sB[e >> 4][e & 15] = rb[cur][i];
        }
        if (st + 1 < NSTAGE) {
            const size_t to = (size_t)(st + 1) * SCHUNK;
            #pragma unroll
            for (int i = 0; i < SCHUNK; ++i) {
                rd[nxt][i] = pD[(to + i) * 4096];
                ru[nxt][i] = pU[(to + i) * 2048];
            }
            #pragma unroll
            for (int i = 0; i < 2; ++i) {
                int e = i * 64 + tid;
                rb[nxt][i] = pB[(to + (e >> 4)) * 96 + (e & 15)];
            }
        }
        #pragma unroll
        for (int s = 0; s < SCHUNK; ++s) {
            float delta = rd[cur][s];
            float du    = delta * ru[cur][s];
            dsum += delta;
            #pragma unroll
            for (int q = 0; q < 4; ++q) {
                float4 bq = *(const float4*)&sB[s][q * 4];
                h[q*4+0] = h[q*4+0] * fexp2(delta * Al[q*4+0]) + du * bq.x;
                h[q*4+1] = h[q*4+1] * fexp2(delta * Al[q*4+1]) + du * bq.y;
                h[q*4+2] = h[q*4+2] * fexp2(delta * Al[q*4+2]) + du * bq.z;
                h[q*4+3] = h[q*4+3] * fexp2(delta * Al[q*4+3]) + du * bq.w;
            }
        }
    }

    size_t base = (((size_t)b * DIN + d) * GCHUNK + chunk) * NST;
    #pragma unroll
    for (int q = 0; q < 4; ++q)
        *(float4*)&c_out[base + q * 4] = make_float4(h[q*4], h[q*4+1], h[q*4+2], h[q*4+3]);
    dsum_out[((size_t)b * DIN + d) * GCHUNK + chunk] = dsum;
}

// ---------------------------------------------------------------------------
// Pass 2: per (b,d,n) scan the 64 chunk summaries, IN PLACE over c_buf.
// ---------------------------------------------------------------------------
__global__ __launch_bounds__(256) void scan_part2(
    float* __restrict__ cbuf,           // in: c, out: h_start
    const float* __restrict__ dsum_in,  // [2][2048][64]
    const float* __restrict__ A_log)
{
    int idx = blockIdx.x * 256 + threadIdx.x;
    int n   = idx & 15;
    int d   = (idx >> 4) & (DIN - 1);
    int b   = idx >> 15;

    float Al = -__expf(A_log[(size_t)d * NST + n]) * LOG2E;
    size_t cb = ((size_t)b * DIN + d) * GCHUNK;

    float h = 0.f;
    for (int ch = 0; ch < GCHUNK; ++ch) {
        size_t o = (cb + ch) * NST + n;
        float c  = cbuf[o];
        float dA = fexp2(Al * dsum_in[cb + ch]);
        cbuf[o]  = h;
        h = h * dA + c;
    }
}

// ---------------------------------------------------------------------------
// Pass 3: register-pipelined, z-gate + y output (fp32 in-place over uconv).
// ---------------------------------------------------------------------------
__global__ __launch_bounds__(64) void scan_part3(
    const float* __restrict__ xz,       // delta cols 0:2048, z cols 2048:4096
    float* __restrict__ uconv,          // in: u, out: y
    const float* __restrict__ dbc,
    const float* __restrict__ A_log,
    const float* __restrict__ Dp,
    const float* __restrict__ h_start)
{
    int chunk = blockIdx.x & 63;
    int dg    = (blockIdx.x >> 6) & 31;
    int b     = blockIdx.x >> 11;
    int tid   = threadIdx.x;
    int d     = dg * 64 + tid;

    __shared__ float sBC[SCHUNK][32];   // [s][0:16]=B, [s][16:32]=C

    float Al[NST];
    const float4* pA = (const float4*)(A_log + (size_t)d * NST);
    #pragma unroll
    for (int q = 0; q < 4; ++q) {
        float4 a = pA[q];
        Al[q*4+0] = -__expf(a.x) * LOG2E;
        Al[q*4+1] = -__expf(a.y) * LOG2E;
        Al[q*4+2] = -__expf(a.z) * LOG2E;
        Al[q*4+3] = -__expf(a.w) * LOG2E;
    }
    float Dd = Dp[d];

    float h[NST];
    size_t hb = (((size_t)b * DIN + d) * GCHUNK + chunk) * NST;
    #pragma unroll
    for (int q = 0; q < 4; ++q) {
        float4 v = *(const float4*)&h_start[hb + q * 4];
        h[q*4] = v.x; h[q*4+1] = v.y; h[q*4+2] = v.z; h[q*4+3] = v.w;
    }

    const size_t tokbase = (size_t)b * L_SEQ + (size_t)chunk * CLEN;
    const float* pD = xz    + tokbase * 4096 + d;
    const float* pZ = xz    + tokbase * 4096 + 2048 + d;
    const float* pU = uconv + tokbase * 2048 + d;
    const float* pB = dbc   + tokbase * 96 + RRANK;
    float*       pY = uconv + tokbase * 2048 + d;

    float rd[2][SCHUNK], ru[2][SCHUNK], rz[2][SCHUNK], rb[2][4];

    #pragma unroll
    for (int i = 0; i < SCHUNK; ++i) {
        rd[0][i] = pD[(size_t)i * 4096];
        ru[0][i] = pU[(size_t)i * 2048];
        rz[0][i] = pZ[(size_t)i * 4096];
    }
    #pragma unroll
    for (int i = 0; i < 4; ++i) {
        int e = i * 64 + tid;
        rb[0][i] = pB[(size_t)(e >> 5) * 96 + (e & 31)];
    }

    #pragma unroll
    for (int st = 0; st < NSTAGE; ++st) {
        const int cur = st & 1, nxt = cur ^ 1;
        #pragma unroll
        for (int i = 0; i < 4; ++i) {
            int e = i * 64 + tid;
            sBC[e >> 5][e & 31] = rb[cur][i];
        }
        if (st + 1 < NSTAGE) {
            const size_t to = (size_t)(st + 1) * SCHUNK;
            #pragma unroll
            for (int i = 0; i < SCHUNK; ++i) {
                rd[nxt][i] = pD[(to + i) * 4096];
                ru[nxt][i] = pU[(to + i) * 2048];
                rz[nxt][i] = pZ[(to + i) * 4096];
            }
            #pragma unroll
            for (int i = 0; i < 4; ++i) {
                int e = i * 64 + tid;
                rb[nxt][i] = pB[(to + (e >> 5)) * 96 + (e & 31)];
            }
        }
        #pragma unroll
        for (int s = 0; s < SCHUNK; ++s) {
            float delta = rd[cur][s];
            float u     = ru[cur][s];
            float du    = delta * u;
            float y = 0.f;
            #pragma unroll
            for (int q = 0; q < 4; ++q) {
                float4 bq = *(const float4*)&sBC[s][q * 4];
                float4 cq = *(const float4*)&sBC[s][16 + q * 4];
                h[q*4+0] = h[q*4+0] * fexp2(delta * Al[q*4+0]) + du * bq.x; y += h[q*4+0] * cq.x;
                h[q*4+1] = h[q*4+1] * fexp2(delta * Al[q*4+1]) + du * bq.y; y += h[q*4+1] * cq.y;
                h[q*4+2] = h[q*4+2] * fexp2(delta * Al[q*4+2]) + du * bq.z; y += h[q*4+2] * cq.z;
                h[q*4+3] = h[q*4+3] * fexp2(delta * Al[q*4+3]) + du * bq.w; y += h[q*4+3] * cq.w;
            }
            float z  = rz[cur][s];
            float sz = z / (1.f + __expf(-z));
            pY[((size_t)st * SCHUNK + s) * 2048] = (y + u * Dd) * sz;
        }
    }
}

// ---------------------------------------------------------------------------
// Fused split-K reduce (bf16 partials) + LayerNorm + residual.
// ---------------------------------------------------------------------------
__global__ __launch_bounds__(256) void ln4_k(
    const ushort* __restrict__ part,  // [4][4096][1024] bf16
    const float* __restrict__ x,
    const float* __restrict__ gamma, const float* __restrict__ beta,
    float* __restrict__ out)
{
    int row = blockIdx.x;
    int tid = threadIdx.x;
    const size_t off = (size_t)row * DMOD + tid * 4;

    float4 v = {0.f, 0.f, 0.f, 0.f};
    #pragma unroll
    for (int ks = 0; ks < G4_KS; ++ks) {
        ushort4 p = *(const ushort4*)(part + (size_t)ks * NTOK * DMOD + off);
        v.x += bf2f(p.x); v.y += bf2f(p.y); v.z += bf2f(p.z); v.w += bf2f(p.w);
    }

    float s  = v.x + v.y + v.z + v.w;
    float s2 = v.x * v.x + v.y * v.y + v.z * v.z + v.w * v.w;
    #pragma unroll
    for (int off2 = 32; off2 > 0; off2 >>= 1) {
        s  += __shfl_down(s, off2);
        s2 += __shfl_down(s2, off2);
    }
    __shared__ float ws[4], ws2[4];
    int wave = tid >> 6, lane = tid & 63;
    if (lane == 0) { ws[wave] = s; ws2[wave] = s2; }
    __syncthreads();
    if (tid == 0) {
        float ts = 0.f, ts2 = 0.f;
        #pragma unroll
        for (int w = 0; w < 4; ++w) { ts += ws[w]; ts2 += ws2[w]; }
        ws[0] = ts; ws2[0] = ts2;
    }
    __syncthreads();
    float mu  = ws[0] * (1.f / DMOD);
    float var = ws2[0] * (1.f / DMOD) - mu * mu;
    float rs  = rsqrtf(var + 1e-5f);

    float4 g  = ((const float4*)gamma)[tid];
    float4 be = ((const float4*)beta)[tid];
    float4 xr = *(const float4*)(x + off);
    float4 o;
    o.x = (v.x - mu) * rs * g.x + be.x + xr.x;
    o.y = (v.y - mu) * rs * g.y + be.y + xr.y;
    o.z = (v.z - mu) * rs * g.z + be.z + xr.z;
    o.w = (v.w - mu) * rs * g.w + be.w + xr.w;
    *(float4*)(out + off) = o;
}

// ---------------------------------------------------------------------------
extern "C" void kernel_launch(void* const* d_in, const int* in_sizes, int n_in,
                              void* d_out, int out_size, void* d_ws, size_t ws_size,
                              hipStream_t stream)
{
    const float* x      = (const float*)d_in[0];
    const float* W_in   = (const float*)d_in[1];
    const float* w_conv = (const float*)d_in[2];
    const float* b_conv = (const float*)d_in[3];
    const float* W_x    = (const float*)d_in[4];
    const float* W_dt   = (const float*)d_in[5];
    const float* b_dt   = (const float*)d_in[6];
    const float* A_log  = (const float*)d_in[7];
    const float* Dp     = (const float*)d_in[8];
    const float* W_out  = (const float*)d_in[9];
    const float* gamma  = (const float*)d_in[10];
    const float* beta   = (const float*)d_in[11];
    float* out = (float*)d_out;

    char* ws = (char*)d_ws;
    const size_t MB = 1024 * 1024;
    // Alive long-term:
    float* xz     = (float*)(ws);                            // [4096][4096] (0-64 MB)
    float* uconv  = (float*)(ws + 64 * MB);                  // [4096][2048] (64-96)
    float* dbc    = (float*)(ws + 96 * MB);                  // [4096][96]   (96-97.5)
    // Wdtb: prep -> GEMM3; same bytes later become dsum (written by scan1).
    ushort* Wdtb  = (ushort*)(ws + 97 * MB + 512 * 1024);    // [2048][64] bf16 (0.25 MB)
    float* dsum   = (float*)(ws + 97 * MB + 512 * 1024);     // [2][2048][64] (1 MB, scan phase)
    float* c_buf  = (float*)(ws + 98 * MB + 512 * 1024);     // [2][2048][64][16] (16 MB, scan)
    // pre-GEMM1 (dead after GEMM1; overlays c_buf zone):
    ushort* xb    = (ushort*)(ws + 98 * MB + 512 * 1024);    // [4096][1024] bf16 (8 MB)
    ushort* Wib   = (ushort*)(ws + 106 * MB + 512 * 1024);   // [4096][1024] bf16 (8 MB)
    // GEMM2 phase (dead after reduce; overlays c_buf zone):
    float* g2part = (float*)(ws + 98 * MB + 512 * 1024);     // [8][4096][96] (12.6 MB)
    // dtb: g2reduce -> GEMM3; above g2part end (111.1), below c_buf end (114.5).
    ushort* dtb   = (ushort*)(ws + 111 * MB + 512 * 1024);   // [4096][64] bf16 (0.5 MB)
    // post-scan phase (xz dead after scan_part3):
    ushort* yb    = (ushort*)(ws);                           // [4096][2048] bf16 (0-16)
    ushort* Wob   = (ushort*)(ws + 16 * MB);                 // [1024][2048] bf16 (16-20)
    ushort* g4part = (ushort*)(ws + 32 * MB);                // [4][4096][1024] bf16 (32-64)

    dim3 blk(256);

    // 1. prep: x->xb, W_in^T->Wib, W_dt^T->Wdtb   (fused, 6272 blocks)
    prep_k<<<dim3(6272), blk, 0, stream>>>(x, W_in, W_dt, xb, Wib, Wdtb);
    // 2. xz = x @ W_in   (MFMA bf16, BK=32 swizzled)
    gemm_mfma<0><<<dim3(4096 / 128, 4096 / 128), blk, 0, stream>>>(
        xb, Wib, xz, 4096, 4096, 1024, 4096, nullptr);
    // 3. u = silu(causal_conv(u)) -> uconv
    conv_silu_k<<<dim3(NTOK * DIN / 256), blk, 0, stream>>>(xz, w_conv, b_conv, uconv);
    // 4. dbc = u @ W_x  (fp32 split-K + reduce w/ fused dt cast)
    gemm2_splitk<<<dim3(G2_KSPLIT, 64), blk, 0, stream>>>(uconv, W_x, g2part);
    gemm2_reduce_dt<<<dim3(NTOK * 96 / 4 / 256), blk, 0, stream>>>(g2part, dbc, dtb);
    // 5. delta = softplus(dt @ W_dt + b_dt) -> u-half of xz  (MFMA bf16)
    gemm_mfma<1><<<dim3(2048 / 128, 4096 / 128), blk, 0, stream>>>(
        dtb, Wdtb, xz, 4096, 2048, 64, 4096, b_dt);
    // 6. chunked selective scan -> y overwrites uconv
    scan_part1<<<dim3(NBATCH * 32 * GCHUNK), dim3(64), 0, stream>>>(
        xz, uconv, dbc, A_log, c_buf, dsum);
    scan_part2<<<dim3(NBATCH * DIN * NST / 256), blk, 0, stream>>>(
        c_buf, dsum, A_log);
    scan_part3<<<dim3(NBATCH * 32 * GCHUNK), dim3(64), 0, stream>>>(
        xz, uconv, dbc, A_log, Dp, c_buf);
    // 7. post: y->yb bf16 + W_out^T->Wob  (fused, 6144 blocks; xz dead)
    post_k<<<dim3(6144), blk, 0, stream>>>(uconv, W_out, yb, Wob);
    // 8. split-K MFMA: bf16 partials
    gemm4_splitk<<<dim3(32, 8, G4_KS), blk, 0, stream>>>(yb, Wob, g4part);
    // 9. fused reduce + LayerNorm + residual
    ln4_k<<<dim3(NTOK), blk, 0, stream>>>(g4part, x, gamma, beta, out);
}

// Round 10
// 361.266 us; speedup vs baseline: 1.2798x; 1.1027x over previous
//
#include <hip/hip_runtime.h>
#include <math.h>

#define L_SEQ 2048
#define DMOD  1024
#define DIN   2048
#define NBATCH 2
#define NTOK  (NBATCH * L_SEQ)   // 4096 tokens
#define NST   16
#define RRANK 64
#define LOG2E 1.44269504088896f

#define GCHUNK 64                 // chunks along L
#define CLEN   (L_SEQ / GCHUNK)   // 32 steps per chunk
#define SCHUNK 8                  // software-pipeline stage depth
#define NSTAGE (CLEN / SCHUNK)    // 4 stages per chunk

#define G4_KS   4                 // GEMM4 split-K factor
#define G4_KC   (2048 / G4_KS)    // 512 k per slice
#define G2_KS   16                // GEMM2 split-K factor
#define G2_KC   (2048 / G2_KS)    // 128 k per slice

typedef __attribute__((ext_vector_type(8))) short  short8;   // 8 bf16
typedef __attribute__((ext_vector_type(4))) float  f32x4;

__device__ __forceinline__ ushort f2bf(float f) {
    unsigned u = __float_as_uint(f);
    u += 0x7fffu + ((u >> 16) & 1u);
    return (ushort)(u >> 16);
}
__device__ __forceinline__ float bf2f(ushort u) {
    return __uint_as_float(((unsigned)u) << 16);
}
__device__ __forceinline__ float fexp2(float x) {
    return __builtin_amdgcn_exp2f(x);
}

// async global->LDS DMA, 16 B per lane; lds dest = wave-uniform base + lane*16
__device__ __forceinline__ void gload16(const ushort* g, ushort* l) {
    __builtin_amdgcn_global_load_lds(
        (const __attribute__((address_space(1))) unsigned int*)g,
        (__attribute__((address_space(3))) unsigned int*)l,
        16, 0, 0);
}

// ---------------------------------------------------------------------------
// Device helpers: flat cast (2048 elems/block) and 32x32 transpose-cast tile.
// ---------------------------------------------------------------------------
__device__ __forceinline__ void cast_body(
    const float* __restrict__ src, ushort* __restrict__ dst, int bid, int tid)
{
    int i = (bid * 256 + tid) * 8;
    float4 a = *(const float4*)(src + i);
    float4 b = *(const float4*)(src + i + 4);
    ushort4 o0 = make_ushort4(f2bf(a.x), f2bf(a.y), f2bf(a.z), f2bf(a.w));
    ushort4 o1 = make_ushort4(f2bf(b.x), f2bf(b.y), f2bf(b.z), f2bf(b.w));
    *(ushort4*)(dst + i)     = o0;
    *(ushort4*)(dst + i + 4) = o1;
}

__device__ __forceinline__ void tcast_body(
    const float* __restrict__ src, ushort* __restrict__ dst,
    int R, int C, int bx, int by, int tid)
{
    __shared__ float t[32][33];
    int tx = tid & 31;
    int ty = tid >> 5;          // 0..7
    int c0 = bx * 32;
    int r0 = by * 32;
    #pragma unroll
    for (int i = 0; i < 4; ++i)
        t[ty + i * 8][tx] = src[(size_t)(r0 + ty + i * 8) * C + c0 + tx];
    __syncthreads();
    #pragma unroll
    for (int i = 0; i < 4; ++i)
        dst[(size_t)(c0 + ty + i * 8) * R + r0 + tx] = f2bf(t[tx][ty + i * 8]);
}

// ---------------------------------------------------------------------------
// Fused prep: x cast + ALL weight transpose-casts in one launch.
// blocks [0,2048): x->xb ; [2048,6144): W_in^T ; [6144,6272): W_dt^T ;
// [6272,6464): W_x^T ; [6464,8512): W_out^T.
// ---------------------------------------------------------------------------
__global__ __launch_bounds__(256) void prep_k(
    const float* __restrict__ x, const float* __restrict__ W_in,
    const float* __restrict__ W_dt, const float* __restrict__ W_x,
    const float* __restrict__ W_out,
    ushort* __restrict__ xb, ushort* __restrict__ Wib,
    ushort* __restrict__ Wdtb, ushort* __restrict__ Wxb,
    ushort* __restrict__ Wob)
{
    int bid = blockIdx.x, tid = threadIdx.x;
    if (bid < 2048) {
        cast_body(x, xb, bid, tid);
    } else if (bid < 6144) {
        int t = bid - 2048;                 // W_in: R=1024, C=4096
        tcast_body(W_in, Wib, 1024, 4096, t & 127, t >> 7, tid);
    } else if (bid < 6272) {
        int t = bid - 6144;                 // W_dt: R=64, C=2048
        tcast_body(W_dt, Wdtb, 64, 2048, t & 63, t >> 6, tid);
    } else if (bid < 6464) {
        int t = bid - 6272;                 // W_x: R=2048, C=96 -> [96][2048]
        tcast_body(W_x, Wxb, 2048, 96, t % 3, t / 3, tid);
    } else {
        int t = bid - 6464;                 // W_out: R=2048, C=1024
        tcast_body(W_out, Wob, 2048, 1024, t & 31, t >> 5, tid);
    }
}

// ---------------------------------------------------------------------------
// bf16 MFMA GEMM, BK=32 + XOR-swizzled LDS (conflict-free, verified r9).
// OBF=1: bf16 output. EPI=1: softplus(acc + bias[col]) (fp32 out only).
// C(M,N) = A(M,K) @ Bt(N,K)^T. 128x128 tile, 4 waves. K%32==0.
// ---------------------------------------------------------------------------
template<int EPI, int OBF>
__global__ __launch_bounds__(256) void gemm_mfma(
    const ushort* __restrict__ A,   // [M][K] bf16
    const ushort* __restrict__ Bt,  // [N][K] bf16
    void* __restrict__ Cv,          // fp32 or bf16, leading dim ldc
    int M, int N, int K, int ldc, const float* __restrict__ bias)
{
    __shared__ ushort As[128 * 32];   // 8 KB
    __shared__ ushort Bs[128 * 32];

    const int tid  = threadIdx.x;
    const int wave = tid >> 6;
    const int lane = tid & 63;
    const int wm   = (wave & 1) * 64;
    const int wn   = (wave >> 1) * 64;
    const int m0   = blockIdx.y * 128;
    const int n0   = blockIdx.x * 128;

    const int srow = lane >> 2;                       // 0..15
    const int sg   = (lane & 3) ^ ((srow >> 1) & 3);  // swizzled src granule
    const ushort* gA0 = A  + (size_t)(m0 + wave * 32 + srow)      * K + sg * 8;
    const ushort* gA1 = A  + (size_t)(m0 + wave * 32 + 16 + srow) * K + sg * 8;
    const ushort* gB0 = Bt + (size_t)(n0 + wave * 32 + srow)      * K + sg * 8;
    const ushort* gB1 = Bt + (size_t)(n0 + wave * 32 + 16 + srow) * K + sg * 8;
    ushort* lA0 = As + (wave * 32)      * 32;
    ushort* lA1 = As + (wave * 32 + 16) * 32;
    ushort* lB0 = Bs + (wave * 32)      * 32;
    ushort* lB1 = Bs + (wave * 32 + 16) * 32;

    const int lrow = lane & 15;
    const int swr  = ((lane >> 4) ^ ((lrow >> 1) & 3)) * 8;

    f32x4 acc[4][4];
    #pragma unroll
    for (int i = 0; i < 4; ++i)
        #pragma unroll
        for (int j = 0; j < 4; ++j)
            acc[i][j] = (f32x4){0.f, 0.f, 0.f, 0.f};

    for (int k0 = 0; k0 < K; k0 += 32) {
        __syncthreads();
        gload16(gA0 + k0, lA0);
        gload16(gA1 + k0, lA1);
        gload16(gB0 + k0, lB0);
        gload16(gB1 + k0, lB1);
        __syncthreads();

        short8 af[4], bfr[4];
        #pragma unroll
        for (int i = 0; i < 4; ++i) {
            af[i]  = *(const short8*)&As[(wm + i * 16 + lrow) * 32 + swr];
            bfr[i] = *(const short8*)&Bs[(wn + i * 16 + lrow) * 32 + swr];
        }
        #pragma unroll
        for (int i = 0; i < 4; ++i)
            #pragma unroll
            for (int j = 0; j < 4; ++j)
                acc[i][j] = __builtin_amdgcn_mfma_f32_16x16x32_bf16(
                    af[i], bfr[j], acc[i][j], 0, 0, 0);
    }

    // C/D layout: col = lane&15, row = (lane>>4)*4 + reg
    const int rb = m0 + wm + ((lane >> 4) << 2);
    const int cb = n0 + wn + lrow;
    #pragma unroll
    for (int i = 0; i < 4; ++i)
        #pragma unroll
        for (int j = 0; j < 4; ++j)
            #pragma unroll
            for (int r = 0; r < 4; ++r) {
                float v = acc[i][j][r];
                int col = cb + j * 16;
                if (EPI == 1) {
                    v += bias[col];
                    v = (v > 20.f) ? v : log1pf(__expf(v));  // softplus
                }
                size_t off = (size_t)(rb + i * 16 + r) * ldc + col;
                if (OBF) ((ushort*)Cv)[off] = f2bf(v);
                else     ((float*)Cv)[off]  = v;
            }
}

// ---------------------------------------------------------------------------
// GEMM2 MFMA split-K: part[ks] (fp32) = ub @ Wxb^T over 128-k slice.
// Grid (32 m, 1, 16 ks). N=96: B-staging rows clamped, store col-guarded.
// ---------------------------------------------------------------------------
__global__ __launch_bounds__(256) void gemm2_mfma(
    const ushort* __restrict__ A,   // [4096][2048] bf16 = ub
    const ushort* __restrict__ Bt,  // [96][2048] bf16 = Wxb
    float* __restrict__ part)       // [16][4096][96] fp32
{
    __shared__ ushort As[128 * 32];
    __shared__ ushort Bs[128 * 32];

    const int K = 2048;
    const int tid  = threadIdx.x;
    const int wave = tid >> 6;
    const int lane = tid & 63;
    const int wm   = (wave & 1) * 64;
    const int wn   = (wave >> 1) * 64;
    const int m0   = blockIdx.x * 128;
    const int ks   = blockIdx.z;

    const int srow = lane >> 2;
    const int sg   = (lane & 3) ^ ((srow >> 1) & 3);
    int rB0 = wave * 32 + srow;      if (rB0 > 95) rB0 = 95;
    int rB1 = wave * 32 + 16 + srow; if (rB1 > 95) rB1 = 95;
    const ushort* gA0 = A  + (size_t)(m0 + wave * 32 + srow)      * K + sg * 8;
    const ushort* gA1 = A  + (size_t)(m0 + wave * 32 + 16 + srow) * K + sg * 8;
    const ushort* gB0 = Bt + (size_t)rB0 * K + sg * 8;
    const ushort* gB1 = Bt + (size_t)rB1 * K + sg * 8;
    ushort* lA0 = As + (wave * 32)      * 32;
    ushort* lA1 = As + (wave * 32 + 16) * 32;
    ushort* lB0 = Bs + (wave * 32)      * 32;
    ushort* lB1 = Bs + (wave * 32 + 16) * 32;

    const int lrow = lane & 15;
    const int swr  = ((lane >> 4) ^ ((lrow >> 1) & 3)) * 8;

    f32x4 acc[4][4];
    #pragma unroll
    for (int i = 0; i < 4; ++i)
        #pragma unroll
        for (int j = 0; j < 4; ++j)
            acc[i][j] = (f32x4){0.f, 0.f, 0.f, 0.f};

    const int kbeg = ks * G2_KC, kend = kbeg + G2_KC;
    for (int k0 = kbeg; k0 < kend; k0 += 32) {
        __syncthreads();
        gload16(gA0 + k0, lA0);
        gload16(gA1 + k0, lA1);
        gload16(gB0 + k0, lB0);
        gload16(gB1 + k0, lB1);
        __syncthreads();

        short8 af[4], bfr[4];
        #pragma unroll
        for (int i = 0; i < 4; ++i) {
            af[i]  = *(const short8*)&As[(wm + i * 16 + lrow) * 32 + swr];
            bfr[i] = *(const short8*)&Bs[(wn + i * 16 + lrow) * 32 + swr];
        }
        #pragma unroll
        for (int i = 0; i < 4; ++i)
            #pragma unroll
            for (int j = 0; j < 4; ++j)
                acc[i][j] = __builtin_amdgcn_mfma_f32_16x16x32_bf16(
                    af[i], bfr[j], acc[i][j], 0, 0, 0);
    }

    float* po = part + (size_t)ks * NTOK * 96;
    const int rb = m0 + wm + ((lane >> 4) << 2);
    const int cb = wn + lrow;
    #pragma unroll
    for (int i = 0; i < 4; ++i)
        #pragma unroll
        for (int j = 0; j < 4; ++j) {
            int col = cb + j * 16;
            if (col < 96) {
                #pragma unroll
                for (int r = 0; r < 4; ++r)
                    po[(size_t)(rb + i * 16 + r) * 96 + col] = acc[i][j][r];
            }
        }
}

// ---------------------------------------------------------------------------
// GEMM2 reduce (16 slices) + fused dt bf16 cast (cols 0:64 -> dtb).
// ---------------------------------------------------------------------------
__global__ __launch_bounds__(256) void gemm2_reduce_dt(
    const float* __restrict__ part, float* __restrict__ dbc,
    ushort* __restrict__ dtb)
{
    int i = (blockIdx.x * 256 + threadIdx.x) * 4;
    float4 s = *(const float4*)(part + i);
    #pragma unroll
    for (int ks = 1; ks < G2_KS; ++ks) {
        float4 v = *(const float4*)(part + (size_t)ks * NTOK * 96 + i);
        s.x += v.x; s.y += v.y; s.z += v.z; s.w += v.w;
    }
    *(float4*)(dbc + i) = s;
    int col = i % 96;
    if (col < RRANK) {
        int row = i / 96;
        ushort* q = dtb + (size_t)row * RRANK + col;
        q[0] = f2bf(s.x); q[1] = f2bf(s.y); q[2] = f2bf(s.z); q[3] = f2bf(s.w);
    }
}

// ---------------------------------------------------------------------------
// Causal depthwise conv (K=4) + SiLU, bf16 in (xzb u-half) / bf16 out (ub).
// ---------------------------------------------------------------------------
__global__ __launch_bounds__(256) void conv_silu_k(
    const ushort* __restrict__ xzb, const float* __restrict__ w_conv,
    const float* __restrict__ b_conv, ushort* __restrict__ ub)
{
    int idx   = blockIdx.x * 256 + threadIdx.x;
    int d     = idx & (DIN - 1);
    int token = idx >> 11;
    int t     = token & (L_SEQ - 1);

    float acc = b_conv[d];
    #pragma unroll
    for (int k = 0; k < 4; ++k) {
        int tt = t - 3 + k;
        if (tt >= 0)
            acc += bf2f(xzb[(size_t)(token - 3 + k) * 4096 + d]) * w_conv[d * 4 + k];
    }
    float s = acc / (1.f + expf(-acc));
    ub[(size_t)token * DIN + d] = f2bf(s);
}

// ---------------------------------------------------------------------------
// Scan pass 1: 1-wave blocks, register-pipelined, no barriers.
// delta fp32 from dlt; u bf16 from ub.
// ---------------------------------------------------------------------------
__global__ __launch_bounds__(64) void scan_part1(
    const float* __restrict__ dlt,     // [4096][2048] fp32
    const ushort* __restrict__ ub,     // [4096][2048] bf16
    const float* __restrict__ dbc,
    const float* __restrict__ A_log,
    float* __restrict__ c_out,         // [2][2048][64][16]
    float* __restrict__ dsum_out)      // [2][2048][64]
{
    int chunk = blockIdx.x & 63;
    int dg    = (blockIdx.x >> 6) & 31;
    int b     = blockIdx.x >> 11;
    int tid   = threadIdx.x;
    int d     = dg * 64 + tid;

    __shared__ float sB[SCHUNK][16];

    float Al[NST];
    const float4* pA = (const float4*)(A_log + (size_t)d * NST);
    #pragma unroll
    for (int q = 0; q < 4; ++q) {
        float4 a = pA[q];
        Al[q*4+0] = -__expf(a.x) * LOG2E;
        Al[q*4+1] = -__expf(a.y) * LOG2E;
        Al[q*4+2] = -__expf(a.z) * LOG2E;
        Al[q*4+3] = -__expf(a.w) * LOG2E;
    }

    float h[NST];
    #pragma unroll
    for (int n = 0; n < NST; ++n) h[n] = 0.f;
    float dsum = 0.f;

    const size_t tokbase = (size_t)b * L_SEQ + (size_t)chunk * CLEN;
    const float*  pD = dlt + tokbase * 2048 + d;
    const ushort* pU = ub  + tokbase * 2048 + d;
    const float*  pB = dbc + tokbase * 96 + RRANK;

    float rd[2][SCHUNK], ru[2][SCHUNK], rb[2][2];

    #pragma unroll
    for (int i = 0; i < SCHUNK; ++i) {
        rd[0][i] = pD[(size_t)i * 2048];
        ru[0][i] = bf2f(pU[(size_t)i * 2048]);
    }
    #pragma unroll
    for (int i = 0; i < 2; ++i) {
        int e = i * 64 + tid;
        rb[0][i] = pB[(size_t)(e >> 4) * 96 + (e & 15)];
    }

    #pragma unroll
    for (int st = 0; st < NSTAGE; ++st) {
        const int cur = st & 1, nxt = cur ^ 1;
        #pragma unroll
        for (int i = 0; i < 2; ++i) {
            int e = i * 64 + tid;
            sB[e >> 4][e & 15] = rb[cur][i];
        }
        if (st + 1 < NSTAGE) {
            const size_t to = (size_t)(st + 1) * SCHUNK;
            #pragma unroll
            for (int i = 0; i < SCHUNK; ++i) {
                rd[nxt][i] = pD[(to + i) * 2048];
                ru[nxt][i] = bf2f(pU[(to + i) * 2048]);
            }
            #pragma unroll
            for (int i = 0; i < 2; ++i) {
                int e = i * 64 + tid;
                rb[nxt][i] = pB[(to + (e >> 4)) * 96 + (e & 15)];
            }
        }
        #pragma unroll
        for (int s = 0; s < SCHUNK; ++s) {
            float delta = rd[cur][s];
            float du    = delta * ru[cur][s];
            dsum += delta;
            #pragma unroll
            for (int q = 0; q < 4; ++q) {
                float4 bq = *(const float4*)&sB[s][q * 4];
                h[q*4+0] = h[q*4+0] * fexp2(delta * Al[q*4+0]) + du * bq.x;
                h[q*4+1] = h[q*4+1] * fexp2(delta * Al[q*4+1]) + du * bq.y;
                h[q*4+2] = h[q*4+2] * fexp2(delta * Al[q*4+2]) + du * bq.z;
                h[q*4+3] = h[q*4+3] * fexp2(delta * Al[q*4+3]) + du * bq.w;
            }
        }
    }

    size_t base = (((size_t)b * DIN + d) * GCHUNK + chunk) * NST;
    #pragma unroll
    for (int q = 0; q < 4; ++q)
        *(float4*)&c_out[base + q * 4] = make_float4(h[q*4], h[q*4+1], h[q*4+2], h[q*4+3]);
    dsum_out[((size_t)b * DIN + d) * GCHUNK + chunk] = dsum;
}

// ---------------------------------------------------------------------------
// Pass 2: per (b,d,n) scan the 64 chunk summaries, IN PLACE over c_buf.
// ---------------------------------------------------------------------------
__global__ __launch_bounds__(256) void scan_part2(
    float* __restrict__ cbuf,
    const float* __restrict__ dsum_in,
    const float* __restrict__ A_log)
{
    int idx = blockIdx.x * 256 + threadIdx.x;
    int n   = idx & 15;
    int d   = (idx >> 4) & (DIN - 1);
    int b   = idx >> 15;

    float Al = -__expf(A_log[(size_t)d * NST + n]) * LOG2E;
    size_t cb = ((size_t)b * DIN + d) * GCHUNK;

    float h = 0.f;
    for (int ch = 0; ch < GCHUNK; ++ch) {
        size_t o = (cb + ch) * NST + n;
        float c  = cbuf[o];
        float dA = fexp2(Al * dsum_in[cb + ch]);
        cbuf[o]  = h;
        h = h * dA + c;
    }
}

// ---------------------------------------------------------------------------
// Pass 3: register-pipelined; u/z bf16 in, y bf16 out IN-PLACE over ub.
// ---------------------------------------------------------------------------
__global__ __launch_bounds__(64) void scan_part3(
    const float* __restrict__ dlt,      // delta fp32
    const ushort* __restrict__ xzb,     // z in cols 2048:4096 (bf16)
    ushort* __restrict__ ub,            // in: u bf16, out: y bf16
    const float* __restrict__ dbc,
    const float* __restrict__ A_log,
    const float* __restrict__ Dp,
    const float* __restrict__ h_start)
{
    int chunk = blockIdx.x & 63;
    int dg    = (blockIdx.x >> 6) & 31;
    int b     = blockIdx.x >> 11;
    int tid   = threadIdx.x;
    int d     = dg * 64 + tid;

    __shared__ float sBC[SCHUNK][32];   // [s][0:16]=B, [s][16:32]=C

    float Al[NST];
    const float4* pA = (const float4*)(A_log + (size_t)d * NST);
    #pragma unroll
    for (int q = 0; q < 4; ++q) {
        float4 a = pA[q];
        Al[q*4+0] = -__expf(a.x) * LOG2E;
        Al[q*4+1] = -__expf(a.y) * LOG2E;
        Al[q*4+2] = -__expf(a.z) * LOG2E;
        Al[q*4+3] = -__expf(a.w) * LOG2E;
    }
    float Dd = Dp[d];

    float h[NST];
    size_t hb = (((size_t)b * DIN + d) * GCHUNK + chunk) * NST;
    #pragma unroll
    for (int q = 0; q < 4; ++q) {
        float4 v = *(const float4*)&h_start[hb + q * 4];
        h[q*4] = v.x; h[q*4+1] = v.y; h[q*4+2] = v.z; h[q*4+3] = v.w;
    }

    const size_t tokbase = (size_t)b * L_SEQ + (size_t)chunk * CLEN;
    const float*  pD = dlt + tokbase * 2048 + d;
    const ushort* pZ = xzb + tokbase * 4096 + 2048 + d;
    ushort*       pU = ub  + tokbase * 2048 + d;
    const float*  pB = dbc + tokbase * 96 + RRANK;

    float rd[2][SCHUNK], ru[2][SCHUNK], rz[2][SCHUNK], rb[2][4];

    #pragma unroll
    for (int i = 0; i < SCHUNK; ++i) {
        rd[0][i] = pD[(size_t)i * 2048];
        ru[0][i] = bf2f(pU[(size_t)i * 2048]);
        rz[0][i] = bf2f(pZ[(size_t)i * 4096]);
    }
    #pragma unroll
    for (int i = 0; i < 4; ++i) {
        int e = i * 64 + tid;
        rb[0][i] = pB[(size_t)(e >> 5) * 96 + (e & 31)];
    }

    #pragma unroll
    for (int st = 0; st < NSTAGE; ++st) {
        const int cur = st & 1, nxt = cur ^ 1;
        #pragma unroll
        for (int i = 0; i < 4; ++i) {
            int e = i * 64 + tid;
            sBC[e >> 5][e & 31] = rb[cur][i];
        }
        if (st + 1 < NSTAGE) {
            const size_t to = (size_t)(st + 1) * SCHUNK;
            #pragma unroll
            for (int i = 0; i < SCHUNK; ++i) {
                rd[nxt][i] = pD[(to + i) * 2048];
                ru[nxt][i] = bf2f(pU[(to + i) * 2048]);
                rz[nxt][i] = bf2f(pZ[(to + i) * 4096]);
            }
            #pragma unroll
            for (int i = 0; i < 4; ++i) {
                int e = i * 64 + tid;
                rb[nxt][i] = pB[(to + (e >> 5)) * 96 + (e & 31)];
            }
        }
        #pragma unroll
        for (int s = 0; s < SCHUNK; ++s) {
            float delta = rd[cur][s];
            float u     = ru[cur][s];
            float du    = delta * u;
            float y = 0.f;
            #pragma unroll
            for (int q = 0; q < 4; ++q) {
                float4 bq = *(const float4*)&sBC[s][q * 4];
                float4 cq = *(const float4*)&sBC[s][16 + q * 4];
                h[q*4+0] = h[q*4+0] * fexp2(delta * Al[q*4+0]) + du * bq.x; y += h[q*4+0] * cq.x;
                h[q*4+1] = h[q*4+1] * fexp2(delta * Al[q*4+1]) + du * bq.y; y += h[q*4+1] * cq.y;
                h[q*4+2] = h[q*4+2] * fexp2(delta * Al[q*4+2]) + du * bq.z; y += h[q*4+2] * cq.z;
                h[q*4+3] = h[q*4+3] * fexp2(delta * Al[q*4+3]) + du * bq.w; y += h[q*4+3] * cq.w;
            }
            float z  = rz[cur][s];
            float sz = z / (1.f + __expf(-z));
            pU[((size_t)st * SCHUNK + s) * 2048] = f2bf((y + u * Dd) * sz);
        }
    }
}

// ---------------------------------------------------------------------------
// GEMM4 split-K MFMA: part[ks] (bf16) = y(ub) @ Wob^T slice. m-major grid.
// ---------------------------------------------------------------------------
__global__ __launch_bounds__(256) void gemm4_splitk(
    const ushort* __restrict__ A,   // [4096][2048] bf16 (y)
    const ushort* __restrict__ Bt,  // [1024][2048] bf16
    ushort* __restrict__ part)      // [4][4096][1024] bf16
{
    __shared__ ushort As[128 * 32];
    __shared__ ushort Bs[128 * 32];

    const int K = 2048;
    const int tid  = threadIdx.x;
    const int wave = tid >> 6;
    const int lane = tid & 63;
    const int wm   = (wave & 1) * 64;
    const int wn   = (wave >> 1) * 64;
    const int m0   = blockIdx.x * 128;       // m-major!
    const int n0   = blockIdx.y * 128;
    const int ks   = blockIdx.z;

    const int srow = lane >> 2;
    const int sg   = (lane & 3) ^ ((srow >> 1) & 3);
    const ushort* gA0 = A  + (size_t)(m0 + wave * 32 + srow)      * K + sg * 8;
    const ushort* gA1 = A  + (size_t)(m0 + wave * 32 + 16 + srow) * K + sg * 8;
    const ushort* gB0 = Bt + (size_t)(n0 + wave * 32 + srow)      * K + sg * 8;
    const ushort* gB1 = Bt + (size_t)(n0 + wave * 32 + 16 + srow) * K + sg * 8;
    ushort* lA0 = As + (wave * 32)      * 32;
    ushort* lA1 = As + (wave * 32 + 16) * 32;
    ushort* lB0 = Bs + (wave * 32)      * 32;
    ushort* lB1 = Bs + (wave * 32 + 16) * 32;

    const int lrow = lane & 15;
    const int swr  = ((lane >> 4) ^ ((lrow >> 1) & 3)) * 8;

    f32x4 acc[4][4];
    #pragma unroll
    for (int i = 0; i < 4; ++i)
        #pragma unroll
        for (int j = 0; j < 4; ++j)
            acc[i][j] = (f32x4){0.f, 0.f, 0.f, 0.f};

    const int kbeg = ks * G4_KC, kend = kbeg + G4_KC;
    for (int k0 = kbeg; k0 < kend; k0 += 32) {
        __syncthreads();
        gload16(gA0 + k0, lA0);
        gload16(gA1 + k0, lA1);
        gload16(gB0 + k0, lB0);
        gload16(gB1 + k0, lB1);
        __syncthreads();

        short8 af[4], bfr[4];
        #pragma unroll
        for (int i = 0; i < 4; ++i) {
            af[i]  = *(const short8*)&As[(wm + i * 16 + lrow) * 32 + swr];
            bfr[i] = *(const short8*)&Bs[(wn + i * 16 + lrow) * 32 + swr];
        }
        #pragma unroll
        for (int i = 0; i < 4; ++i)
            #pragma unroll
            for (int j = 0; j < 4; ++j)
                acc[i][j] = __builtin_amdgcn_mfma_f32_16x16x32_bf16(
                    af[i], bfr[j], acc[i][j], 0, 0, 0);
    }

    ushort* Cp = part + (size_t)ks * NTOK * DMOD;
    const int rb = m0 + wm + ((lane >> 4) << 2);
    const int cb = n0 + wn + lrow;
    #pragma unroll
    for (int i = 0; i < 4; ++i)
        #pragma unroll
        for (int j = 0; j < 4; ++j)
            #pragma unroll
            for (int r = 0; r < 4; ++r)
                Cp[(size_t)(rb + i * 16 + r) * DMOD + cb + j * 16] = f2bf(acc[i][j][r]);
}

// ---------------------------------------------------------------------------
// Fused split-K reduce (bf16 partials) + LayerNorm + residual.
// ---------------------------------------------------------------------------
__global__ __launch_bounds__(256) void ln4_k(
    const ushort* __restrict__ part,  // [4][4096][1024] bf16
    const float* __restrict__ x,
    const float* __restrict__ gamma, const float* __restrict__ beta,
    float* __restrict__ out)
{
    int row = blockIdx.x;
    int tid = threadIdx.x;
    const size_t off = (size_t)row * DMOD + tid * 4;

    float4 v = {0.f, 0.f, 0.f, 0.f};
    #pragma unroll
    for (int ks = 0; ks < G4_KS; ++ks) {
        ushort4 p = *(const ushort4*)(part + (size_t)ks * NTOK * DMOD + off);
        v.x += bf2f(p.x); v.y += bf2f(p.y); v.z += bf2f(p.z); v.w += bf2f(p.w);
    }

    float s  = v.x + v.y + v.z + v.w;
    float s2 = v.x * v.x + v.y * v.y + v.z * v.z + v.w * v.w;
    #pragma unroll
    for (int off2 = 32; off2 > 0; off2 >>= 1) {
        s  += __shfl_down(s, off2);
        s2 += __shfl_down(s2, off2);
    }
    __shared__ float ws[4], ws2[4];
    int wave = tid >> 6, lane = tid & 63;
    if (lane == 0) { ws[wave] = s; ws2[wave] = s2; }
    __syncthreads();
    if (tid == 0) {
        float ts = 0.f, ts2 = 0.f;
        #pragma unroll
        for (int w = 0; w < 4; ++w) { ts += ws[w]; ts2 += ws2[w]; }
        ws[0] = ts; ws2[0] = ts2;
    }
    __syncthreads();
    float mu  = ws[0] * (1.f / DMOD);
    float var = ws2[0] * (1.f / DMOD) - mu * mu;
    float rs  = rsqrtf(var + 1e-5f);

    float4 g  = ((const float4*)gamma)[tid];
    float4 be = ((const float4*)beta)[tid];
    float4 xr = *(const float4*)(x + off);
    float4 o;
    o.x = (v.x - mu) * rs * g.x + be.x + xr.x;
    o.y = (v.y - mu) * rs * g.y + be.y + xr.y;
    o.z = (v.z - mu) * rs * g.z + be.z + xr.z;
    o.w = (v.w - mu) * rs * g.w + be.w + xr.w;
    *(float4*)(out + off) = o;
}

// ---------------------------------------------------------------------------
extern "C" void kernel_launch(void* const* d_in, const int* in_sizes, int n_in,
                              void* d_out, int out_size, void* d_ws, size_t ws_size,
                              hipStream_t stream)
{
    const float* x      = (const float*)d_in[0];
    const float* W_in   = (const float*)d_in[1];
    const float* w_conv = (const float*)d_in[2];
    const float* b_conv = (const float*)d_in[3];
    const float* W_x    = (const float*)d_in[4];
    const float* W_dt   = (const float*)d_in[5];
    const float* b_dt   = (const float*)d_in[6];
    const float* A_log  = (const float*)d_in[7];
    const float* Dp     = (const float*)d_in[8];
    const float* W_out  = (const float*)d_in[9];
    const float* gamma  = (const float*)d_in[10];
    const float* beta   = (const float*)d_in[11];
    float* out = (float*)d_out;

    char* ws = (char*)d_ws;
    const size_t MB = 1024 * 1024;
    // Long-lived:
    ushort* xzb   = (ushort*)(ws);                          // [4096][4096] bf16 (0-32)
    ushort* ub    = (ushort*)(ws + 32 * MB);                // [4096][2048] bf16 (32-48); y in-place after scan3
    float*  dlt   = (float*)(ws + 48 * MB);                 // [4096][2048] fp32 (48-80); dead after scan3
    float*  dbc   = (float*)(ws + 80 * MB);                 // [4096][96] fp32 (80-81.5)
    ushort* Wdtb  = (ushort*)(ws + 81 * MB + 512 * 1024);   // [2048][64] bf16 (0.25 MB)
    ushort* Wxb   = (ushort*)(ws + 81 * MB + 768 * 1024);   // [96][2048] bf16 (0.375 MB)
    float*  dsum  = (float*)(ws + 82 * MB + 256 * 1024);    // [2][2048][64] (1 MB)
    float*  c_buf = (float*)(ws + 84 * MB);                 // [2][2048][64][16] (16 MB, 84-100)
    // prep phase (dead after GEMM1; overlays c_buf zone):
    ushort* xb    = (ushort*)(ws + 84 * MB);                // [4096][1024] bf16 (8 MB)
    ushort* Wib   = (ushort*)(ws + 92 * MB);                // [4096][1024] bf16 (8 MB)
    // GEMM2 phase (dead after reduce; overlays c_buf + beyond):
    float*  g2part = (float*)(ws + 84 * MB);                // [16][4096][96] fp32 (24 MB, 84-108)
    ushort* dtb   = (ushort*)(ws + 108 * MB);               // [4096][64] bf16 (0.5 MB)
    ushort* Wob   = (ushort*)(ws + 109 * MB);               // [1024][2048] bf16 (4 MB, 109-113)
    // GEMM4 partials overlay dlt (dead after scan3):
    ushort* g4part = (ushort*)(ws + 48 * MB);               // [4][4096][1024] bf16 (32 MB)

    dim3 blk(256);

    // 1. prep: x cast + all 4 weight transposes (8512 blocks)
    prep_k<<<dim3(8512), blk, 0, stream>>>(x, W_in, W_dt, W_x, W_out,
                                           xb, Wib, Wdtb, Wxb, Wob);
    // 2. xz = x @ W_in  -> bf16 xzb
    gemm_mfma<0, 1><<<dim3(32, 32), blk, 0, stream>>>(
        xb, Wib, xzb, 4096, 4096, 1024, 4096, nullptr);
    // 3. u = silu(conv(u)) -> bf16 ub
    conv_silu_k<<<dim3(NTOK * DIN / 256), blk, 0, stream>>>(xzb, w_conv, b_conv, ub);
    // 4. dbc = u @ W_x  (MFMA split-K=16 + reduce w/ dt cast)
    gemm2_mfma<<<dim3(32, 1, G2_KS), blk, 0, stream>>>(ub, Wxb, g2part);
    gemm2_reduce_dt<<<dim3(NTOK * 96 / 4 / 256), blk, 0, stream>>>(g2part, dbc, dtb);
    // 5. delta = softplus(dt @ W_dt + b_dt) -> fp32 dlt
    gemm_mfma<1, 0><<<dim3(16, 32), blk, 0, stream>>>(
        dtb, Wdtb, dlt, 4096, 2048, 64, 2048, b_dt);
    // 6. chunked selective scan; y bf16 overwrites ub
    scan_part1<<<dim3(NBATCH * 32 * GCHUNK), dim3(64), 0, stream>>>(
        dlt, ub, dbc, A_log, c_buf, dsum);
    scan_part2<<<dim3(NBATCH * DIN * NST / 256), blk, 0, stream>>>(
        c_buf, dsum, A_log);
    scan_part3<<<dim3(NBATCH * 32 * GCHUNK), dim3(64), 0, stream>>>(
        dlt, xzb, ub, dbc, A_log, Dp, c_buf);
    // 7. out_pre partials = y @ W_out^T  (split-K, bf16 partials; dlt dead)
    gemm4_splitk<<<dim3(32, 8, G4_KS), blk, 0, stream>>>(ub, Wob, g4part);
    // 8. fused reduce + LayerNorm + residual
    ln4_k<<<dim3(NTOK), blk, 0, stream>>>(g4part, x, gamma, beta, out);
}